// Round 9
// baseline (1336.089 us; speedup 1.0000x reference)
//
#include <hip/hip_runtime.h>

#define H 128
#define ED 64
#define CH 16
#define SCB 256
#define SCT 256

typedef __attribute__((ext_vector_type(8))) short short8;
typedef __attribute__((ext_vector_type(4))) float f32x4;

// stats layout: [0:128) colsum, [128:256) colsumsq, [256:384) scale, [384:512) shift
__device__ __align__(16) float g_stats[512];

__device__ __forceinline__ unsigned short f2bf(float f) {
    unsigned u = __float_as_uint(f);
    unsigned r = u + 0x7fffu + ((u >> 16) & 1u);   // RNE
    return (unsigned short)(r >> 16);
}
__device__ __forceinline__ float bf2f(unsigned short h) {
    return __uint_as_float(((unsigned)h) << 16);
}

__global__ void k_zero_stats() {
    if (threadIdx.x < 512) g_stats[threadIdx.x] = 0.f;
}

// ================= padded-tile CSR build =================
__global__ void k_hist(const int* __restrict__ ei, int* __restrict__ cnt, int E) {
    for (int e = blockIdx.x * blockDim.x + threadIdx.x; e < E;
         e += gridDim.x * blockDim.x)
        atomicAdd(&cnt[ei[E + e]], 1);
}

__global__ __launch_bounds__(SCT) void k_scanA(const int* __restrict__ cnt,
                                               int* __restrict__ bsum, int N) {
    __shared__ int part[SCT];
    const int b = blockIdx.x, t = threadIdx.x;
    const int chunk = (N + SCB - 1) / SCB;
    const int tch = (chunk + SCT - 1) / SCT;
    const int lo = b * chunk + t * tch;
    const int hi = min(lo + tch, min((b + 1) * chunk, N));
    int s = 0;
    for (int i = lo; i < hi; ++i) s += (cnt[i] + 15) >> 4;
    part[t] = s;
    __syncthreads();
    for (int d = SCT / 2; d > 0; d >>= 1) {
        if (t < d) part[t] += part[t + d];
        __syncthreads();
    }
    if (t == 0) bsum[b] = part[0];
}

__global__ __launch_bounds__(SCB) void k_scanB(const int* __restrict__ bsum,
                                               int* __restrict__ bpre,
                                               int* __restrict__ toffN) {
    __shared__ int part[SCB];
    const int t = threadIdx.x;
    int v = bsum[t];
    part[t] = v;
    __syncthreads();
    for (int d = 1; d < SCB; d <<= 1) {
        int x = (t >= d) ? part[t - d] : 0;
        __syncthreads();
        part[t] += x;
        __syncthreads();
    }
    bpre[t] = part[t] - v;
    if (t == SCB - 1) *toffN = part[t];
}

__global__ __launch_bounds__(SCT) void k_scanC(const int* __restrict__ cnt,
                                               const int* __restrict__ bpre,
                                               int* __restrict__ toff,
                                               int* __restrict__ tileDst, int N) {
    __shared__ int part[SCT];
    const int b = blockIdx.x, t = threadIdx.x;
    const int chunk = (N + SCB - 1) / SCB;
    const int tch = (chunk + SCT - 1) / SCT;
    const int lo = b * chunk + t * tch;
    const int hi = min(lo + tch, min((b + 1) * chunk, N));
    int ls = 0;
    for (int i = lo; i < hi; ++i) ls += (cnt[i] + 15) >> 4;
    part[t] = ls;
    __syncthreads();
    for (int d = 1; d < SCT; d <<= 1) {
        int x = (t >= d) ? part[t - d] : 0;
        __syncthreads();
        part[t] += x;
        __syncthreads();
    }
    int run = bpre[b] + part[t] - ls;
    for (int i = lo; i < hi; ++i) {
        toff[i] = run;
        int c = (cnt[i] + 15) >> 4;
        for (int j = 0; j < c; ++j) tileDst[run + j] = i;
        run += c;
    }
}

__global__ void k_fillp(const int* __restrict__ ei, const int* __restrict__ toff,
                        int* __restrict__ cur, int* __restrict__ tilePerm, int E) {
    for (int e = blockIdx.x * blockDim.x + threadIdx.x; e < E;
         e += gridDim.x * blockDim.x) {
        int d = ei[E + e];
        int pos = atomicAdd(&cur[d], 1);
        int tile = toff[d] + (pos >> 4);
        tilePerm[(tile << 4) + (pos & 15)] = e;
    }
}

// ================= Edge kernel: padded tiles, deep pipeline, 2 atomics/tile ====
// A lane map: row = lane&15, k = 8*(lane>>4)+b (+32 2nd K-step)
// C/D lane map: col = lane&15, row = 4*(lane>>4)+reg   (HW-verified r5-r8)
// launch_bounds(256,5): VGPR budget 102 (uses ~84) -> ~20 waves/CU vs r8's 12.
__global__ __launch_bounds__(256, 5) void k_edge_t(
    const float* __restrict__ hN, const int* __restrict__ ei,
    const float* __restrict__ ea, const float* __restrict__ We,
    const float* __restrict__ be, const int* __restrict__ toff,
    const int* __restrict__ tileDst, const int* __restrict__ tilePerm,
    float* __restrict__ agg, int N, int E)
{
    __shared__ __align__(16) short sBf[8][2][64][8];   // 16 KB B-fragments
    const int tid = threadIdx.x;
    for (int idx = tid; idx < 8 * 2 * 64; idx += 256) {
        int t = idx >> 7, s = (idx >> 6) & 1, ll = idx & 63;
        int ra = ll & 15, kgg = ll >> 4;
        short8 f;
#pragma unroll
        for (int b = 0; b < 8; ++b) {
            int k = (s << 5) + (kgg << 3) + b;
            f[b] = (short)f2bf(We[k * H + (t << 4) + ra]);
        }
        *(short8*)&sBf[t][s][ll][0] = f;
    }
    const int l = tid & 63, w = tid >> 6;
    const int rA = l & 15, kg = l >> 4;
    float beT[8];
#pragma unroll
    for (int t = 0; t < 8; ++t) beT[t] = be[(t << 4) + rA];
    __syncthreads();

    const int nT = toff[N];
    const int gw = (blockIdx.x << 2) | w;
    const int nW = gridDim.x << 2;
    if (gw >= nT) return;

    int peC, srcC, dstC;
    float4 ea0, ea1, ea2, ea3;
    int peN;
    {
        peC = tilePerm[(gw << 4) + rA];
        dstC = tileDst[gw];
        srcC = (peC >= 0) ? ei[peC] : -1;
        const float* ar = ea + (size_t)max(peC, 0) * ED + (kg << 3);
        ea0 = *(const float4*)ar;        ea1 = *(const float4*)(ar + 4);
        ea2 = *(const float4*)(ar + 32); ea3 = *(const float4*)(ar + 36);
        peN = (gw + nW < nT) ? tilePerm[((gw + nW) << 4) + rA] : -1;
    }

    for (int tt = gw; tt < nT; tt += nW) {
        // 1) distribute srcs, issue hv gathers
        const int s0 = __shfl(srcC, (kg << 2) + 0);
        const int s1 = __shfl(srcC, (kg << 2) + 1);
        const int s2 = __shfl(srcC, (kg << 2) + 2);
        const int s3 = __shfl(srcC, (kg << 2) + 3);
        float hv0[8], hv1[8], hv2[8], hv3[8];
        {
            const float* hp0 = hN + (size_t)max(s0, 0) * H + rA;
            const float* hp1 = hN + (size_t)max(s1, 0) * H + rA;
            const float* hp2 = hN + (size_t)max(s2, 0) * H + rA;
            const float* hp3 = hN + (size_t)max(s3, 0) * H + rA;
#pragma unroll
            for (int t = 0; t < 8; ++t) {
                hv0[t] = hp0[t << 4]; hv1[t] = hp1[t << 4];
                hv2[t] = hp2[t << 4]; hv3[t] = hp3[t << 4];
            }
        }
        // 2) next tile's src/dst/ea via peN
        const int ttN = tt + nW;
        int srcN = -1, dstN = 0;
        float4 eb0, eb1, eb2, eb3;
        eb0 = eb1 = eb2 = eb3 = make_float4(0.f, 0.f, 0.f, 0.f);
        if (ttN < nT) {
            srcN = (peN >= 0) ? ei[peN] : -1;
            dstN = tileDst[ttN];
            const float* ar = ea + (size_t)max(peN, 0) * ED + (kg << 3);
            eb0 = *(const float4*)ar;        eb1 = *(const float4*)(ar + 4);
            eb2 = *(const float4*)(ar + 32); eb3 = *(const float4*)(ar + 36);
        }
        // 3) depth-2 linear perm prefetch
        const int ttF = tt + 2 * nW;
        const int peF = (ttF < nT) ? tilePerm[(ttF << 4) + rA] : -1;

        // 4) cvt A -> bf16, 16 MFMAs
        short8 A0, A1;
        A0[0] = f2bf(ea0.x); A0[1] = f2bf(ea0.y); A0[2] = f2bf(ea0.z); A0[3] = f2bf(ea0.w);
        A0[4] = f2bf(ea1.x); A0[5] = f2bf(ea1.y); A0[6] = f2bf(ea1.z); A0[7] = f2bf(ea1.w);
        A1[0] = f2bf(ea2.x); A1[1] = f2bf(ea2.y); A1[2] = f2bf(ea2.z); A1[3] = f2bf(ea2.w);
        A1[4] = f2bf(ea3.x); A1[5] = f2bf(ea3.y); A1[6] = f2bf(ea3.z); A1[7] = f2bf(ea3.w);
        f32x4 C[8];
#pragma unroll
        for (int t = 0; t < 8; ++t) {
            short8 b0 = *(const short8*)&sBf[t][0][l][0];
            short8 b1 = *(const short8*)&sBf[t][1][l][0];
            f32x4 c = __builtin_amdgcn_mfma_f32_16x16x32_bf16(
                A0, b0, (f32x4){0.f, 0.f, 0.f, 0.f}, 0, 0, 0);
            C[t] = __builtin_amdgcn_mfma_f32_16x16x32_bf16(A1, b1, c, 0, 0, 0);
        }

        // 5) epilogue: relu(msg + h + be), column reduce, 2 atomics
        const float ok0 = (s0 >= 0) ? 1.f : 0.f;
        const float ok1 = (s1 >= 0) ? 1.f : 0.f;
        const float ok2 = (s2 >= 0) ? 1.f : 0.f;
        const float ok3 = (s3 >= 0) ? 1.f : 0.f;
        float pacc[8];
#pragma unroll
        for (int t = 0; t < 8; ++t) {
            float v = fmaxf(C[t][0] + hv0[t] + beT[t], 0.f) * ok0
                    + fmaxf(C[t][1] + hv1[t] + beT[t], 0.f) * ok1
                    + fmaxf(C[t][2] + hv2[t] + beT[t], 0.f) * ok2
                    + fmaxf(C[t][3] + hv3[t] + beT[t], 0.f) * ok3;
            v += __shfl_xor(v, 16);
            v += __shfl_xor(v, 32);
            pacc[t] = v;
        }
        float vlo = (kg == 0) ? pacc[0] : (kg == 1) ? pacc[1] : (kg == 2) ? pacc[2] : pacc[3];
        float vhi = (kg == 0) ? pacc[4] : (kg == 1) ? pacc[5] : (kg == 2) ? pacc[6] : pacc[7];
        float* qp = agg + (size_t)dstC * H + l;
        atomicAdd(qp, vlo);
        atomicAdd(qp + 64, vhi);

        peC = peN; srcC = srcN; dstC = dstN;
        ea0 = eb0; ea1 = eb1; ea2 = eb2; ea3 = eb3;
        peN = peF;
    }
}

// ================= MLP layer 1 (MFMA, hi/lo activations) ======================
// 32 KB LDS (frags built straight from global W1) -> 4 blocks/CU.
__global__ __launch_bounds__(256, 4) void k_mlp1(
    const float* __restrict__ hN, float* zb, const float* __restrict__ W1,
    const float* __restrict__ b1, const float* __restrict__ epsp, int N)
{
    __shared__ __align__(16) short sBf[8][4][64][8];   // 32 KB W1 frags
    const int tid = threadIdx.x;
    for (int idx = tid; idx < 8 * 4 * 64; idx += 256) {
        int t = idx >> 8, s = (idx >> 6) & 3, ll = idx & 63;
        int ra = ll & 15, kgg = ll >> 4;
        short8 f;
#pragma unroll
        for (int b = 0; b < 8; ++b) {
            int k = (s << 5) + (kgg << 3) + b;
            f[b] = (short)f2bf(W1[k * H + (t << 4) + ra]);
        }
        *(short8*)&sBf[t][s][ll][0] = f;
    }
    __syncthreads();
    const int l = tid & 63, w = tid >> 6;
    const int rA = l & 15, kg = l >> 4;
    const float e1 = 1.f + epsp[0];
    float bT[8];
#pragma unroll
    for (int t = 0; t < 8; ++t) bT[t] = b1[(t << 4) + rA];

    const int nT = (N + CH - 1) / CH;
    for (int tt = blockIdx.x * 4 + w; tt < nT; tt += gridDim.x * 4) {
        const int n0 = tt << 4;
        const int row = min(n0 + rA, N - 1);
        const float* hrow = hN + (size_t)row * H;
        const float* arow = (const float*)zb + (size_t)row * H;
        f32x4 C[8];
#pragma unroll
        for (int t = 0; t < 8; ++t) C[t] = (f32x4){0.f, 0.f, 0.f, 0.f};

        const float* hp = hrow + (kg << 3);
        const float* ap = arow + (kg << 3);
        float4 h0 = *(const float4*)hp, h1 = *(const float4*)(hp + 4);
        float4 g0 = *(const float4*)ap, g1 = *(const float4*)(ap + 4);
#pragma unroll
        for (int s = 0; s < 4; ++s) {
            float4 h0n, h1n, g0n, g1n;
            if (s < 3) {
                const float* hp2 = hrow + ((s + 1) << 5) + (kg << 3);
                const float* ap2 = arow + ((s + 1) << 5) + (kg << 3);
                h0n = *(const float4*)hp2; h1n = *(const float4*)(hp2 + 4);
                g0n = *(const float4*)ap2; g1n = *(const float4*)(ap2 + 4);
            }
            float z[8];
            z[0] = fmaf(e1, h0.x, g0.x); z[1] = fmaf(e1, h0.y, g0.y);
            z[2] = fmaf(e1, h0.z, g0.z); z[3] = fmaf(e1, h0.w, g0.w);
            z[4] = fmaf(e1, h1.x, g1.x); z[5] = fmaf(e1, h1.y, g1.y);
            z[6] = fmaf(e1, h1.z, g1.z); z[7] = fmaf(e1, h1.w, g1.w);
            short8 ah, al;
#pragma unroll
            for (int j = 0; j < 8; ++j) {
                unsigned short hi = f2bf(z[j]);
                ah[j] = (short)hi;
                al[j] = (short)f2bf(z[j] - bf2f(hi));
            }
#pragma unroll
            for (int t = 0; t < 8; ++t) {
                short8 B = *(const short8*)&sBf[t][s][l][0];
                C[t] = __builtin_amdgcn_mfma_f32_16x16x32_bf16(ah, B, C[t], 0, 0, 0);
                C[t] = __builtin_amdgcn_mfma_f32_16x16x32_bf16(al, B, C[t], 0, 0, 0);
            }
            if (s < 3) { h0 = h0n; h1 = h1n; g0 = g0n; g1 = g1n; }
        }
#pragma unroll
        for (int t = 0; t < 8; ++t) {
#pragma unroll
            for (int rg = 0; rg < 4; ++rg) {
                int n = n0 + (kg << 2) + rg;
                float y = fmaxf(C[t][rg] + bT[t], 0.f);
                unsigned short hi = f2bf(y);
                unsigned short lo = f2bf(y - bf2f(hi));
                if (n < N)
                    ((unsigned*)zb)[(size_t)n * H + (t << 4) + rA] =
                        ((unsigned)hi << 16) | (unsigned)lo;
            }
        }
    }
}

// ================= MLP layer 2 + BN stats =================
__global__ __launch_bounds__(256, 4) void k_mlp2(
    float* zb, const float* __restrict__ W2, const float* __restrict__ b2, int N)
{
    __shared__ __align__(16) short sBf[8][4][64][8];   // 32 KB W2 frags
    const int tid = threadIdx.x;
    for (int idx = tid; idx < 8 * 4 * 64; idx += 256) {
        int t = idx >> 8, s = (idx >> 6) & 3, ll = idx & 63;
        int ra = ll & 15, kgg = ll >> 4;
        short8 f;
#pragma unroll
        for (int b = 0; b < 8; ++b) {
            int k = (s << 5) + (kgg << 3) + b;
            f[b] = (short)f2bf(W2[k * H + (t << 4) + ra]);
        }
        *(short8*)&sBf[t][s][ll][0] = f;
    }
    __syncthreads();
    const int l = tid & 63, w = tid >> 6;
    const int rA = l & 15, kg = l >> 4;
    float bT[8];
#pragma unroll
    for (int t = 0; t < 8; ++t) bT[t] = b2[(t << 4) + rA];
    float ps[8], pq[8];
#pragma unroll
    for (int t = 0; t < 8; ++t) { ps[t] = 0.f; pq[t] = 0.f; }

    const int nT = (N + CH - 1) / CH;
    for (int tt = blockIdx.x * 4 + w; tt < nT; tt += gridDim.x * 4) {
        const int n0 = tt << 4;
        const int row = min(n0 + rA, N - 1);
        const unsigned* yrow = (const unsigned*)zb + (size_t)row * H;
        f32x4 C[8];
#pragma unroll
        for (int t = 0; t < 8; ++t) C[t] = (f32x4){0.f, 0.f, 0.f, 0.f};

        const unsigned* yp = yrow + (kg << 3);
        uint4 u0 = *(const uint4*)yp, u1 = *(const uint4*)(yp + 4);
#pragma unroll
        for (int s = 0; s < 4; ++s) {
            uint4 u0n, u1n;
            if (s < 3) {
                const unsigned* yp2 = yrow + ((s + 1) << 5) + (kg << 3);
                u0n = *(const uint4*)yp2; u1n = *(const uint4*)(yp2 + 4);
            }
            short8 ah, al;
            ah[0] = (short)(u0.x >> 16); al[0] = (short)(u0.x & 0xffffu);
            ah[1] = (short)(u0.y >> 16); al[1] = (short)(u0.y & 0xffffu);
            ah[2] = (short)(u0.z >> 16); al[2] = (short)(u0.z & 0xffffu);
            ah[3] = (short)(u0.w >> 16); al[3] = (short)(u0.w & 0xffffu);
            ah[4] = (short)(u1.x >> 16); al[4] = (short)(u1.x & 0xffffu);
            ah[5] = (short)(u1.y >> 16); al[5] = (short)(u1.y & 0xffffu);
            ah[6] = (short)(u1.z >> 16); al[6] = (short)(u1.z & 0xffffu);
            ah[7] = (short)(u1.w >> 16); al[7] = (short)(u1.w & 0xffffu);
#pragma unroll
            for (int t = 0; t < 8; ++t) {
                short8 B = *(const short8*)&sBf[t][s][l][0];
                C[t] = __builtin_amdgcn_mfma_f32_16x16x32_bf16(ah, B, C[t], 0, 0, 0);
                C[t] = __builtin_amdgcn_mfma_f32_16x16x32_bf16(al, B, C[t], 0, 0, 0);
            }
            if (s < 3) { u0 = u0n; u1 = u1n; }
        }
#pragma unroll
        for (int t = 0; t < 8; ++t) {
#pragma unroll
            for (int rg = 0; rg < 4; ++rg) {
                int n = n0 + (kg << 2) + rg;
                float z2 = fmaxf(C[t][rg] + bT[t], 0.f);
                bool v = (n < N);
                if (v) ((float*)zb)[(size_t)n * H + (t << 4) + rA] = z2;
                float zc = v ? z2 : 0.f;
                ps[t] += zc;
                pq[t] += zc * zc;
            }
        }
    }
#pragma unroll
    for (int t = 0; t < 8; ++t) {
        float a = ps[t]; a += __shfl_xor(a, 16); a += __shfl_xor(a, 32); ps[t] = a;
        float b = pq[t]; b += __shfl_xor(b, 16); b += __shfl_xor(b, 32); pq[t] = b;
    }
    if (l < 16) {
#pragma unroll
        for (int t = 0; t < 8; ++t) {
            atomicAdd(&g_stats[(t << 4) + l], ps[t]);
            atomicAdd(&g_stats[128 + (t << 4) + l], pq[t]);
        }
    }
}

// ================= BN finalize =================
__global__ void k_bnfin(const float* __restrict__ gamma, const float* __restrict__ beta,
                        float invN)
{
    int t = threadIdx.x;
    float mean = g_stats[t] * invN;
    float var  = g_stats[H + t] * invN - mean * mean;
    float sc = gamma[t] * rsqrtf(var + 1e-5f);
    g_stats[256 + t] = sc;
    g_stats[384 + t] = beta[t] - mean * sc;
}

// ================= Final: out = (h + z2*scale + shift) * valid ================
__global__ void k_final(const float* __restrict__ hN, const float* __restrict__ valid,
                        float* __restrict__ out, int N)
{
    const int total = N * (H / 4);
    for (int i = blockIdx.x * blockDim.x + threadIdx.x; i < total;
         i += gridDim.x * blockDim.x) {
        int col4 = i & 31;
        int n = i >> 5;
        float4 z = ((float4*)out)[i];
        float4 hv = ((const float4*)hN)[i];
        float4 sc = *(const float4*)&g_stats[256 + col4 * 4];
        float4 sh = *(const float4*)&g_stats[384 + col4 * 4];
        float vf = valid[n];
        float4 r;
        r.x = (hv.x + fmaf(z.x, sc.x, sh.x)) * vf;
        r.y = (hv.y + fmaf(z.y, sc.y, sh.y)) * vf;
        r.z = (hv.z + fmaf(z.z, sc.z, sh.z)) * vf;
        r.w = (hv.w + fmaf(z.w, sc.w, sh.w)) * vf;
        ((float4*)out)[i] = r;
    }
}

// ================= Fallback (ws too small): natural-order atomic MFMA =========
__global__ __launch_bounds__(512, 4) void k_edge_a(
    const float* __restrict__ hN, const int* __restrict__ ei,
    const float* __restrict__ ea, const float* __restrict__ We,
    const float* __restrict__ be, float* __restrict__ agg, int E)
{
    __shared__ __align__(16) short sBf[8][2][64][8];
    const int tid = threadIdx.x;
    for (int idx = tid; idx < 8 * 2 * 64; idx += 512) {
        int t = idx >> 7, s = (idx >> 6) & 1, ll = idx & 63;
        int ra = ll & 15, kgg = ll >> 4;
        short8 f;
#pragma unroll
        for (int b = 0; b < 8; ++b) {
            int k = (s << 5) + (kgg << 3) + b;
            f[b] = (short)f2bf(We[k * H + (t << 4) + ra]);
        }
        *(short8*)&sBf[t][s][ll][0] = f;
    }
    const int l = tid & 63, w = tid >> 6;
    const int rA = l & 15, kg = l >> 4;
    float beT[8];
#pragma unroll
    for (int t = 0; t < 8; ++t) beT[t] = be[(t << 4) + rA];
    __syncthreads();

    const int nT = (E + CH - 1) / CH;
    for (int tt = (blockIdx.x << 3) | w; tt < nT; tt += gridDim.x << 3) {
        int e0 = tt * CH;
        const float* ar = ea + (size_t)min(e0 + rA, E - 1) * ED + (kg << 3);
        float4 a0 = *(const float4*)ar,        a1 = *(const float4*)(ar + 4);
        float4 a2 = *(const float4*)(ar + 32), a3 = *(const float4*)(ar + 36);
        int r0 = min(e0 + (kg << 2) + 0, E - 1), r1 = min(e0 + (kg << 2) + 1, E - 1);
        int r2 = min(e0 + (kg << 2) + 2, E - 1), r3 = min(e0 + (kg << 2) + 3, E - 1);
        int s0 = ei[r0], s1 = ei[r1], s2 = ei[r2], s3 = ei[r3];
        int d0 = ei[E + r0], d1 = ei[E + r1], d2 = ei[E + r2], d3 = ei[E + r3];
        float hv0[8], hv1[8], hv2[8], hv3[8];
        const float* hp0 = hN + (size_t)s0 * H + rA;
        const float* hp1 = hN + (size_t)s1 * H + rA;
        const float* hp2 = hN + (size_t)s2 * H + rA;
        const float* hp3 = hN + (size_t)s3 * H + rA;
#pragma unroll
        for (int t = 0; t < 8; ++t) {
            hv0[t] = hp0[t << 4]; hv1[t] = hp1[t << 4];
            hv2[t] = hp2[t << 4]; hv3[t] = hp3[t << 4];
        }
        short8 A0, A1;
        A0[0] = f2bf(a0.x); A0[1] = f2bf(a0.y); A0[2] = f2bf(a0.z); A0[3] = f2bf(a0.w);
        A0[4] = f2bf(a1.x); A0[5] = f2bf(a1.y); A0[6] = f2bf(a1.z); A0[7] = f2bf(a1.w);
        A1[0] = f2bf(a2.x); A1[1] = f2bf(a2.y); A1[2] = f2bf(a2.z); A1[3] = f2bf(a2.w);
        A1[4] = f2bf(a3.x); A1[5] = f2bf(a3.y); A1[6] = f2bf(a3.z); A1[7] = f2bf(a3.w);
        f32x4 C[8];
#pragma unroll
        for (int t = 0; t < 8; ++t) {
            short8 b0 = *(const short8*)&sBf[t][0][l][0];
            short8 b1 = *(const short8*)&sBf[t][1][l][0];
            f32x4 c = __builtin_amdgcn_mfma_f32_16x16x32_bf16(
                A0, b0, (f32x4){0.f, 0.f, 0.f, 0.f}, 0, 0, 0);
            C[t] = __builtin_amdgcn_mfma_f32_16x16x32_bf16(A1, b1, c, 0, 0, 0);
        }
        const int m = E - e0;
        const int r = kg << 2;
        const bool ok0 = (r + 0) < m, ok1 = (r + 1) < m;
        const bool ok2 = (r + 2) < m, ok3 = (r + 3) < m;
        float* q0 = agg + (size_t)d0 * H + rA;
        float* q1 = agg + (size_t)d1 * H + rA;
        float* q2 = agg + (size_t)d2 * H + rA;
        float* q3 = agg + (size_t)d3 * H + rA;
#pragma unroll
        for (int t = 0; t < 8; ++t) {
            if (ok0) atomicAdd(q0 + (t << 4), fmaxf(C[t][0] + hv0[t] + beT[t], 0.f));
            if (ok1) atomicAdd(q1 + (t << 4), fmaxf(C[t][1] + hv1[t] + beT[t], 0.f));
            if (ok2) atomicAdd(q2 + (t << 4), fmaxf(C[t][2] + hv2[t] + beT[t], 0.f));
            if (ok3) atomicAdd(q3 + (t << 4), fmaxf(C[t][3] + hv3[t] + beT[t], 0.f));
        }
    }
}

extern "C" void kernel_launch(void* const* d_in, const int* in_sizes, int n_in,
                              void* d_out, int out_size, void* d_ws, size_t ws_size,
                              hipStream_t stream) {
    const float* hN    = (const float*)d_in[0];
    const int*   ei    = (const int*)d_in[1];
    const float* ea    = (const float*)d_in[2];
    const float* valid = (const float*)d_in[3];
    const float* We    = (const float*)d_in[4];
    const float* be    = (const float*)d_in[5];
    const float* W1    = (const float*)d_in[6];
    const float* b1    = (const float*)d_in[7];
    const float* W2    = (const float*)d_in[8];
    const float* b2    = (const float*)d_in[9];
    const float* epsg  = (const float*)d_in[10];
    const float* gamma = (const float*)d_in[11];
    const float* beta  = (const float*)d_in[12];
    float* out = (float*)d_out;

    const int N = in_sizes[0] / H;
    const int E = in_sizes[1] / 2;

    // ws layout: cnt[N] | cur[N] | toff[N+1] | bsum[SCB] | bpre[SCB] |
    //            tileDst[Tcap] | tilePerm[16*Tcap]
    const int Tcap = (E + 15) / 16 + N;
    const size_t need = ((size_t)3 * N + 1 + 2 * SCB + (size_t)17 * Tcap) * sizeof(int);

    k_zero_stats<<<1, 512, 0, stream>>>();
    hipMemsetAsync(d_out, 0, (size_t)out_size * sizeof(float), stream);

    if (ws_size >= need) {
        int* cnt      = (int*)d_ws;
        int* cur      = cnt + N;
        int* toff     = cur + N;
        int* bsum     = toff + N + 1;
        int* bpre     = bsum + SCB;
        int* tileDst  = bpre + SCB;
        int* tilePerm = tileDst + Tcap;

        hipMemsetAsync(cnt, 0, (size_t)2 * N * sizeof(int), stream);
        hipMemsetAsync(tilePerm, 0xFF, (size_t)16 * Tcap * sizeof(int), stream);
        k_hist<<<2048, 256, 0, stream>>>(ei, cnt, E);
        k_scanA<<<SCB, SCT, 0, stream>>>(cnt, bsum, N);
        k_scanB<<<1, SCB, 0, stream>>>(bsum, bpre, toff + N);
        k_scanC<<<SCB, SCT, 0, stream>>>(cnt, bpre, toff, tileDst, N);
        k_fillp<<<2048, 256, 0, stream>>>(ei, toff, cur, tilePerm, E);
        k_edge_t<<<2048, 256, 0, stream>>>(hN, ei, ea, We, be, toff, tileDst,
                                           tilePerm, out, N, E);
    } else {
        k_edge_a<<<1024, 512, 0, stream>>>(hN, ei, ea, We, be, out, E);
    }

    k_mlp1<<<1024, 256, 0, stream>>>(hN, out, W1, b1, epsg, N);
    k_mlp2<<<1024, 256, 0, stream>>>(out, W2, b2, N);
    k_bnfin<<<1, 128, 0, stream>>>(gamma, beta, 1.0f / (float)N);
    k_final<<<2048, 256, 0, stream>>>(hN, valid, out, N);
}

// Round 10
// 1074.995 us; speedup vs baseline: 1.2429x; 1.2429x over previous
//
#include <hip/hip_runtime.h>

#define H 128
#define ED 64
#define CH 16
#define SCB 256
#define SCT 256

typedef __attribute__((ext_vector_type(8))) short short8;
typedef __attribute__((ext_vector_type(4))) float f32x4;

// stats layout: [0:128) colsum, [128:256) colsumsq, [256:384) scale, [384:512) shift
__device__ __align__(16) float g_stats[512];

__device__ __forceinline__ unsigned short f2bf(float f) {
    unsigned u = __float_as_uint(f);
    unsigned r = u + 0x7fffu + ((u >> 16) & 1u);   // RNE
    return (unsigned short)(r >> 16);
}
__device__ __forceinline__ float bf2f(unsigned short h) {
    return __uint_as_float(((unsigned)h) << 16);
}

__global__ void k_zero_stats() {
    if (threadIdx.x < 512) g_stats[threadIdx.x] = 0.f;
}

// ================= padded-tile CSR build =================
__global__ void k_hist(const int* __restrict__ ei, int* __restrict__ cnt, int E) {
    for (int e = blockIdx.x * blockDim.x + threadIdx.x; e < E;
         e += gridDim.x * blockDim.x)
        atomicAdd(&cnt[ei[E + e]], 1);
}

__global__ __launch_bounds__(SCT) void k_scanA(const int* __restrict__ cnt,
                                               int* __restrict__ bsum, int N) {
    __shared__ int part[SCT];
    const int b = blockIdx.x, t = threadIdx.x;
    const int chunk = (N + SCB - 1) / SCB;
    const int tch = (chunk + SCT - 1) / SCT;
    const int lo = b * chunk + t * tch;
    const int hi = min(lo + tch, min((b + 1) * chunk, N));
    int s = 0;
    for (int i = lo; i < hi; ++i) s += (cnt[i] + 15) >> 4;
    part[t] = s;
    __syncthreads();
    for (int d = SCT / 2; d > 0; d >>= 1) {
        if (t < d) part[t] += part[t + d];
        __syncthreads();
    }
    if (t == 0) bsum[b] = part[0];
}

__global__ __launch_bounds__(SCB) void k_scanB(const int* __restrict__ bsum,
                                               int* __restrict__ bpre,
                                               int* __restrict__ toffN) {
    __shared__ int part[SCB];
    const int t = threadIdx.x;
    int v = bsum[t];
    part[t] = v;
    __syncthreads();
    for (int d = 1; d < SCB; d <<= 1) {
        int x = (t >= d) ? part[t - d] : 0;
        __syncthreads();
        part[t] += x;
        __syncthreads();
    }
    bpre[t] = part[t] - v;
    if (t == SCB - 1) *toffN = part[t];
}

__global__ __launch_bounds__(SCT) void k_scanC(const int* __restrict__ cnt,
                                               const int* __restrict__ bpre,
                                               int* __restrict__ toff,
                                               int* __restrict__ tileDst, int N) {
    __shared__ int part[SCT];
    const int b = blockIdx.x, t = threadIdx.x;
    const int chunk = (N + SCB - 1) / SCB;
    const int tch = (chunk + SCT - 1) / SCT;
    const int lo = b * chunk + t * tch;
    const int hi = min(lo + tch, min((b + 1) * chunk, N));
    int ls = 0;
    for (int i = lo; i < hi; ++i) ls += (cnt[i] + 15) >> 4;
    part[t] = ls;
    __syncthreads();
    for (int d = 1; d < SCT; d <<= 1) {
        int x = (t >= d) ? part[t - d] : 0;
        __syncthreads();
        part[t] += x;
        __syncthreads();
    }
    int run = bpre[b] + part[t] - ls;
    for (int i = lo; i < hi; ++i) {
        toff[i] = run;
        int c = (cnt[i] + 15) >> 4;
        for (int j = 0; j < c; ++j) tileDst[run + j] = i;
        run += c;
    }
}

__global__ void k_fillp(const int* __restrict__ ei, const int* __restrict__ toff,
                        int* __restrict__ cur, int* __restrict__ tilePerm, int E) {
    for (int e = blockIdx.x * blockDim.x + threadIdx.x; e < E;
         e += gridDim.x * blockDim.x) {
        int d = ei[E + e];
        int pos = atomicAdd(&cur[d], 1);
        int tile = toff[d] + (pos >> 4);
        tilePerm[(tile << 4) + (pos & 15)] = e;
    }
}

// ================= Edge kernel: padded tiles, deep pipeline, 2 atomics/tile ====
// A lane map: row = lane&15, k = 8*(lane>>4)+b (+32 2nd K-step)
// C/D lane map: col = lane&15, row = 4*(lane>>4)+reg   (HW-verified r5-r8)
// launch_bounds(256,4): 128-VGPR budget (kernel needs ~84 -> NO spill; r9's
// (256,5) forced 48 VGPR and 2.3 GB of scratch traffic). 4 blocks/CU = 50% occ.
__global__ __launch_bounds__(256, 4) void k_edge_t(
    const float* __restrict__ hN, const int* __restrict__ ei,
    const float* __restrict__ ea, const float* __restrict__ We,
    const float* __restrict__ be, const int* __restrict__ toff,
    const int* __restrict__ tileDst, const int* __restrict__ tilePerm,
    float* __restrict__ agg, int N, int E)
{
    __shared__ __align__(16) short sBf[8][2][64][8];   // 16 KB B-fragments
    const int tid = threadIdx.x;
    for (int idx = tid; idx < 8 * 2 * 64; idx += 256) {
        int t = idx >> 7, s = (idx >> 6) & 1, ll = idx & 63;
        int ra = ll & 15, kgg = ll >> 4;
        short8 f;
#pragma unroll
        for (int b = 0; b < 8; ++b) {
            int k = (s << 5) + (kgg << 3) + b;
            f[b] = (short)f2bf(We[k * H + (t << 4) + ra]);
        }
        *(short8*)&sBf[t][s][ll][0] = f;
    }
    const int l = tid & 63, w = tid >> 6;
    const int rA = l & 15, kg = l >> 4;
    float beT[8];
#pragma unroll
    for (int t = 0; t < 8; ++t) beT[t] = be[(t << 4) + rA];
    __syncthreads();

    const int nT = toff[N];
    const int gw = (blockIdx.x << 2) | w;
    const int nW = gridDim.x << 2;
    if (gw >= nT) return;

    int peC, srcC, dstC;
    float4 ea0, ea1, ea2, ea3;
    int peN;
    {
        peC = tilePerm[(gw << 4) + rA];
        dstC = tileDst[gw];
        srcC = (peC >= 0) ? ei[peC] : -1;
        const float* ar = ea + (size_t)max(peC, 0) * ED + (kg << 3);
        ea0 = *(const float4*)ar;        ea1 = *(const float4*)(ar + 4);
        ea2 = *(const float4*)(ar + 32); ea3 = *(const float4*)(ar + 36);
        peN = (gw + nW < nT) ? tilePerm[((gw + nW) << 4) + rA] : -1;
    }

    for (int tt = gw; tt < nT; tt += nW) {
        // 1) distribute srcs, issue hv gathers
        const int s0 = __shfl(srcC, (kg << 2) + 0);
        const int s1 = __shfl(srcC, (kg << 2) + 1);
        const int s2 = __shfl(srcC, (kg << 2) + 2);
        const int s3 = __shfl(srcC, (kg << 2) + 3);
        float hv0[8], hv1[8], hv2[8], hv3[8];
        {
            const float* hp0 = hN + (size_t)max(s0, 0) * H + rA;
            const float* hp1 = hN + (size_t)max(s1, 0) * H + rA;
            const float* hp2 = hN + (size_t)max(s2, 0) * H + rA;
            const float* hp3 = hN + (size_t)max(s3, 0) * H + rA;
#pragma unroll
            for (int t = 0; t < 8; ++t) {
                hv0[t] = hp0[t << 4]; hv1[t] = hp1[t << 4];
                hv2[t] = hp2[t << 4]; hv3[t] = hp3[t << 4];
            }
        }
        // 2) next tile's src/dst/ea via peN
        const int ttN = tt + nW;
        int srcN = -1, dstN = 0;
        float4 eb0, eb1, eb2, eb3;
        eb0 = eb1 = eb2 = eb3 = make_float4(0.f, 0.f, 0.f, 0.f);
        if (ttN < nT) {
            srcN = (peN >= 0) ? ei[peN] : -1;
            dstN = tileDst[ttN];
            const float* ar = ea + (size_t)max(peN, 0) * ED + (kg << 3);
            eb0 = *(const float4*)ar;        eb1 = *(const float4*)(ar + 4);
            eb2 = *(const float4*)(ar + 32); eb3 = *(const float4*)(ar + 36);
        }
        // 3) depth-2 linear perm prefetch
        const int ttF = tt + 2 * nW;
        const int peF = (ttF < nT) ? tilePerm[(ttF << 4) + rA] : -1;

        // 4) cvt A -> bf16, 16 MFMAs
        short8 A0, A1;
        A0[0] = f2bf(ea0.x); A0[1] = f2bf(ea0.y); A0[2] = f2bf(ea0.z); A0[3] = f2bf(ea0.w);
        A0[4] = f2bf(ea1.x); A0[5] = f2bf(ea1.y); A0[6] = f2bf(ea1.z); A0[7] = f2bf(ea1.w);
        A1[0] = f2bf(ea2.x); A1[1] = f2bf(ea2.y); A1[2] = f2bf(ea2.z); A1[3] = f2bf(ea2.w);
        A1[4] = f2bf(ea3.x); A1[5] = f2bf(ea3.y); A1[6] = f2bf(ea3.z); A1[7] = f2bf(ea3.w);
        f32x4 C[8];
#pragma unroll
        for (int t = 0; t < 8; ++t) {
            short8 b0 = *(const short8*)&sBf[t][0][l][0];
            short8 b1 = *(const short8*)&sBf[t][1][l][0];
            f32x4 c = __builtin_amdgcn_mfma_f32_16x16x32_bf16(
                A0, b0, (f32x4){0.f, 0.f, 0.f, 0.f}, 0, 0, 0);
            C[t] = __builtin_amdgcn_mfma_f32_16x16x32_bf16(A1, b1, c, 0, 0, 0);
        }

        // 5) epilogue: relu(msg + h + be), column reduce, 2 atomics
        const float ok0 = (s0 >= 0) ? 1.f : 0.f;
        const float ok1 = (s1 >= 0) ? 1.f : 0.f;
        const float ok2 = (s2 >= 0) ? 1.f : 0.f;
        const float ok3 = (s3 >= 0) ? 1.f : 0.f;
        float pacc[8];
#pragma unroll
        for (int t = 0; t < 8; ++t) {
            float v = fmaxf(C[t][0] + hv0[t] + beT[t], 0.f) * ok0
                    + fmaxf(C[t][1] + hv1[t] + beT[t], 0.f) * ok1
                    + fmaxf(C[t][2] + hv2[t] + beT[t], 0.f) * ok2
                    + fmaxf(C[t][3] + hv3[t] + beT[t], 0.f) * ok3;
            v += __shfl_xor(v, 16);
            v += __shfl_xor(v, 32);
            pacc[t] = v;
        }
        float vlo = (kg == 0) ? pacc[0] : (kg == 1) ? pacc[1] : (kg == 2) ? pacc[2] : pacc[3];
        float vhi = (kg == 0) ? pacc[4] : (kg == 1) ? pacc[5] : (kg == 2) ? pacc[6] : pacc[7];
        float* qp = agg + (size_t)dstC * H + l;
        atomicAdd(qp, vlo);
        atomicAdd(qp + 64, vhi);

        peC = peN; srcC = srcN; dstC = dstN;
        ea0 = eb0; ea1 = eb1; ea2 = eb2; ea3 = eb3;
        peN = peF;
    }
}

// ================= MLP layer 1 (MFMA, hi/lo activations) ======================
// 32 KB LDS (frags built straight from global W1) -> 4 blocks/CU.
__global__ __launch_bounds__(256, 4) void k_mlp1(
    const float* __restrict__ hN, float* zb, const float* __restrict__ W1,
    const float* __restrict__ b1, const float* __restrict__ epsp, int N)
{
    __shared__ __align__(16) short sBf[8][4][64][8];   // 32 KB W1 frags
    const int tid = threadIdx.x;
    for (int idx = tid; idx < 8 * 4 * 64; idx += 256) {
        int t = idx >> 8, s = (idx >> 6) & 3, ll = idx & 63;
        int ra = ll & 15, kgg = ll >> 4;
        short8 f;
#pragma unroll
        for (int b = 0; b < 8; ++b) {
            int k = (s << 5) + (kgg << 3) + b;
            f[b] = (short)f2bf(W1[k * H + (t << 4) + ra]);
        }
        *(short8*)&sBf[t][s][ll][0] = f;
    }
    __syncthreads();
    const int l = tid & 63, w = tid >> 6;
    const int rA = l & 15, kg = l >> 4;
    const float e1 = 1.f + epsp[0];
    float bT[8];
#pragma unroll
    for (int t = 0; t < 8; ++t) bT[t] = b1[(t << 4) + rA];

    const int nT = (N + CH - 1) / CH;
    for (int tt = blockIdx.x * 4 + w; tt < nT; tt += gridDim.x * 4) {
        const int n0 = tt << 4;
        const int row = min(n0 + rA, N - 1);
        const float* hrow = hN + (size_t)row * H;
        const float* arow = (const float*)zb + (size_t)row * H;
        f32x4 C[8];
#pragma unroll
        for (int t = 0; t < 8; ++t) C[t] = (f32x4){0.f, 0.f, 0.f, 0.f};

        const float* hp = hrow + (kg << 3);
        const float* ap = arow + (kg << 3);
        float4 h0 = *(const float4*)hp, h1 = *(const float4*)(hp + 4);
        float4 g0 = *(const float4*)ap, g1 = *(const float4*)(ap + 4);
#pragma unroll
        for (int s = 0; s < 4; ++s) {
            float4 h0n, h1n, g0n, g1n;
            if (s < 3) {
                const float* hp2 = hrow + ((s + 1) << 5) + (kg << 3);
                const float* ap2 = arow + ((s + 1) << 5) + (kg << 3);
                h0n = *(const float4*)hp2; h1n = *(const float4*)(hp2 + 4);
                g0n = *(const float4*)ap2; g1n = *(const float4*)(ap2 + 4);
            }
            float z[8];
            z[0] = fmaf(e1, h0.x, g0.x); z[1] = fmaf(e1, h0.y, g0.y);
            z[2] = fmaf(e1, h0.z, g0.z); z[3] = fmaf(e1, h0.w, g0.w);
            z[4] = fmaf(e1, h1.x, g1.x); z[5] = fmaf(e1, h1.y, g1.y);
            z[6] = fmaf(e1, h1.z, g1.z); z[7] = fmaf(e1, h1.w, g1.w);
            short8 ah, al;
#pragma unroll
            for (int j = 0; j < 8; ++j) {
                unsigned short hi = f2bf(z[j]);
                ah[j] = (short)hi;
                al[j] = (short)f2bf(z[j] - bf2f(hi));
            }
#pragma unroll
            for (int t = 0; t < 8; ++t) {
                short8 B = *(const short8*)&sBf[t][s][l][0];
                C[t] = __builtin_amdgcn_mfma_f32_16x16x32_bf16(ah, B, C[t], 0, 0, 0);
                C[t] = __builtin_amdgcn_mfma_f32_16x16x32_bf16(al, B, C[t], 0, 0, 0);
            }
            if (s < 3) { h0 = h0n; h1 = h1n; g0 = g0n; g1 = g1n; }
        }
#pragma unroll
        for (int t = 0; t < 8; ++t) {
#pragma unroll
            for (int rg = 0; rg < 4; ++rg) {
                int n = n0 + (kg << 2) + rg;
                float y = fmaxf(C[t][rg] + bT[t], 0.f);
                unsigned short hi = f2bf(y);
                unsigned short lo = f2bf(y - bf2f(hi));
                if (n < N)
                    ((unsigned*)zb)[(size_t)n * H + (t << 4) + rA] =
                        ((unsigned)hi << 16) | (unsigned)lo;
            }
        }
    }
}

// ================= MLP layer 2 + BN stats =================
__global__ __launch_bounds__(256, 4) void k_mlp2(
    float* zb, const float* __restrict__ W2, const float* __restrict__ b2, int N)
{
    __shared__ __align__(16) short sBf[8][4][64][8];   // 32 KB W2 frags
    const int tid = threadIdx.x;
    for (int idx = tid; idx < 8 * 4 * 64; idx += 256) {
        int t = idx >> 8, s = (idx >> 6) & 3, ll = idx & 63;
        int ra = ll & 15, kgg = ll >> 4;
        short8 f;
#pragma unroll
        for (int b = 0; b < 8; ++b) {
            int k = (s << 5) + (kgg << 3) + b;
            f[b] = (short)f2bf(W2[k * H + (t << 4) + ra]);
        }
        *(short8*)&sBf[t][s][ll][0] = f;
    }
    __syncthreads();
    const int l = tid & 63, w = tid >> 6;
    const int rA = l & 15, kg = l >> 4;
    float bT[8];
#pragma unroll
    for (int t = 0; t < 8; ++t) bT[t] = b2[(t << 4) + rA];
    float ps[8], pq[8];
#pragma unroll
    for (int t = 0; t < 8; ++t) { ps[t] = 0.f; pq[t] = 0.f; }

    const int nT = (N + CH - 1) / CH;
    for (int tt = blockIdx.x * 4 + w; tt < nT; tt += gridDim.x * 4) {
        const int n0 = tt << 4;
        const int row = min(n0 + rA, N - 1);
        const unsigned* yrow = (const unsigned*)zb + (size_t)row * H;
        f32x4 C[8];
#pragma unroll
        for (int t = 0; t < 8; ++t) C[t] = (f32x4){0.f, 0.f, 0.f, 0.f};

        const unsigned* yp = yrow + (kg << 3);
        uint4 u0 = *(const uint4*)yp, u1 = *(const uint4*)(yp + 4);
#pragma unroll
        for (int s = 0; s < 4; ++s) {
            uint4 u0n, u1n;
            if (s < 3) {
                const unsigned* yp2 = yrow + ((s + 1) << 5) + (kg << 3);
                u0n = *(const uint4*)yp2; u1n = *(const uint4*)(yp2 + 4);
            }
            short8 ah, al;
            ah[0] = (short)(u0.x >> 16); al[0] = (short)(u0.x & 0xffffu);
            ah[1] = (short)(u0.y >> 16); al[1] = (short)(u0.y & 0xffffu);
            ah[2] = (short)(u0.z >> 16); al[2] = (short)(u0.z & 0xffffu);
            ah[3] = (short)(u0.w >> 16); al[3] = (short)(u0.w & 0xffffu);
            ah[4] = (short)(u1.x >> 16); al[4] = (short)(u1.x & 0xffffu);
            ah[5] = (short)(u1.y >> 16); al[5] = (short)(u1.y & 0xffffu);
            ah[6] = (short)(u1.z >> 16); al[6] = (short)(u1.z & 0xffffu);
            ah[7] = (short)(u1.w >> 16); al[7] = (short)(u1.w & 0xffffu);
#pragma unroll
            for (int t = 0; t < 8; ++t) {
                short8 B = *(const short8*)&sBf[t][s][l][0];
                C[t] = __builtin_amdgcn_mfma_f32_16x16x32_bf16(ah, B, C[t], 0, 0, 0);
                C[t] = __builtin_amdgcn_mfma_f32_16x16x32_bf16(al, B, C[t], 0, 0, 0);
            }
            if (s < 3) { u0 = u0n; u1 = u1n; }
        }
#pragma unroll
        for (int t = 0; t < 8; ++t) {
#pragma unroll
            for (int rg = 0; rg < 4; ++rg) {
                int n = n0 + (kg << 2) + rg;
                float z2 = fmaxf(C[t][rg] + bT[t], 0.f);
                bool v = (n < N);
                if (v) ((float*)zb)[(size_t)n * H + (t << 4) + rA] = z2;
                float zc = v ? z2 : 0.f;
                ps[t] += zc;
                pq[t] += zc * zc;
            }
        }
    }
#pragma unroll
    for (int t = 0; t < 8; ++t) {
        float a = ps[t]; a += __shfl_xor(a, 16); a += __shfl_xor(a, 32); ps[t] = a;
        float b = pq[t]; b += __shfl_xor(b, 16); b += __shfl_xor(b, 32); pq[t] = b;
    }
    if (l < 16) {
#pragma unroll
        for (int t = 0; t < 8; ++t) {
            atomicAdd(&g_stats[(t << 4) + l], ps[t]);
            atomicAdd(&g_stats[128 + (t << 4) + l], pq[t]);
        }
    }
}

// ================= BN finalize =================
__global__ void k_bnfin(const float* __restrict__ gamma, const float* __restrict__ beta,
                        float invN)
{
    int t = threadIdx.x;
    float mean = g_stats[t] * invN;
    float var  = g_stats[H + t] * invN - mean * mean;
    float sc = gamma[t] * rsqrtf(var + 1e-5f);
    g_stats[256 + t] = sc;
    g_stats[384 + t] = beta[t] - mean * sc;
}

// ================= Final: out = (h + z2*scale + shift) * valid ================
__global__ void k_final(const float* __restrict__ hN, const float* __restrict__ valid,
                        float* __restrict__ out, int N)
{
    const int total = N * (H / 4);
    for (int i = blockIdx.x * blockDim.x + threadIdx.x; i < total;
         i += gridDim.x * blockDim.x) {
        int col4 = i & 31;
        int n = i >> 5;
        float4 z = ((float4*)out)[i];
        float4 hv = ((const float4*)hN)[i];
        float4 sc = *(const float4*)&g_stats[256 + col4 * 4];
        float4 sh = *(const float4*)&g_stats[384 + col4 * 4];
        float vf = valid[n];
        float4 r;
        r.x = (hv.x + fmaf(z.x, sc.x, sh.x)) * vf;
        r.y = (hv.y + fmaf(z.y, sc.y, sh.y)) * vf;
        r.z = (hv.z + fmaf(z.z, sc.z, sh.z)) * vf;
        r.w = (hv.w + fmaf(z.w, sc.w, sh.w)) * vf;
        ((float4*)out)[i] = r;
    }
}

// ================= Fallback (ws too small): natural-order atomic MFMA =========
__global__ __launch_bounds__(512, 4) void k_edge_a(
    const float* __restrict__ hN, const int* __restrict__ ei,
    const float* __restrict__ ea, const float* __restrict__ We,
    const float* __restrict__ be, float* __restrict__ agg, int E)
{
    __shared__ __align__(16) short sBf[8][2][64][8];
    const int tid = threadIdx.x;
    for (int idx = tid; idx < 8 * 2 * 64; idx += 512) {
        int t = idx >> 7, s = (idx >> 6) & 1, ll = idx & 63;
        int ra = ll & 15, kgg = ll >> 4;
        short8 f;
#pragma unroll
        for (int b = 0; b < 8; ++b) {
            int k = (s << 5) + (kgg << 3) + b;
            f[b] = (short)f2bf(We[k * H + (t << 4) + ra]);
        }
        *(short8*)&sBf[t][s][ll][0] = f;
    }
    const int l = tid & 63, w = tid >> 6;
    const int rA = l & 15, kg = l >> 4;
    float beT[8];
#pragma unroll
    for (int t = 0; t < 8; ++t) beT[t] = be[(t << 4) + rA];
    __syncthreads();

    const int nT = (E + CH - 1) / CH;
    for (int tt = (blockIdx.x << 3) | w; tt < nT; tt += gridDim.x << 3) {
        int e0 = tt * CH;
        const float* ar = ea + (size_t)min(e0 + rA, E - 1) * ED + (kg << 3);
        float4 a0 = *(const float4*)ar,        a1 = *(const float4*)(ar + 4);
        float4 a2 = *(const float4*)(ar + 32), a3 = *(const float4*)(ar + 36);
        int r0 = min(e0 + (kg << 2) + 0, E - 1), r1 = min(e0 + (kg << 2) + 1, E - 1);
        int r2 = min(e0 + (kg << 2) + 2, E - 1), r3 = min(e0 + (kg << 2) + 3, E - 1);
        int s0 = ei[r0], s1 = ei[r1], s2 = ei[r2], s3 = ei[r3];
        int d0 = ei[E + r0], d1 = ei[E + r1], d2 = ei[E + r2], d3 = ei[E + r3];
        float hv0[8], hv1[8], hv2[8], hv3[8];
        const float* hp0 = hN + (size_t)s0 * H + rA;
        const float* hp1 = hN + (size_t)s1 * H + rA;
        const float* hp2 = hN + (size_t)s2 * H + rA;
        const float* hp3 = hN + (size_t)s3 * H + rA;
#pragma unroll
        for (int t = 0; t < 8; ++t) {
            hv0[t] = hp0[t << 4]; hv1[t] = hp1[t << 4];
            hv2[t] = hp2[t << 4]; hv3[t] = hp3[t << 4];
        }
        short8 A0, A1;
        A0[0] = f2bf(a0.x); A0[1] = f2bf(a0.y); A0[2] = f2bf(a0.z); A0[3] = f2bf(a0.w);
        A0[4] = f2bf(a1.x); A0[5] = f2bf(a1.y); A0[6] = f2bf(a1.z); A0[7] = f2bf(a1.w);
        A1[0] = f2bf(a2.x); A1[1] = f2bf(a2.y); A1[2] = f2bf(a2.z); A1[3] = f2bf(a2.w);
        A1[4] = f2bf(a3.x); A1[5] = f2bf(a3.y); A1[6] = f2bf(a3.z); A1[7] = f2bf(a3.w);
        f32x4 C[8];
#pragma unroll
        for (int t = 0; t < 8; ++t) {
            short8 b0 = *(const short8*)&sBf[t][0][l][0];
            short8 b1 = *(const short8*)&sBf[t][1][l][0];
            f32x4 c = __builtin_amdgcn_mfma_f32_16x16x32_bf16(
                A0, b0, (f32x4){0.f, 0.f, 0.f, 0.f}, 0, 0, 0);
            C[t] = __builtin_amdgcn_mfma_f32_16x16x32_bf16(A1, b1, c, 0, 0, 0);
        }
        const int m = E - e0;
        const int r = kg << 2;
        const bool ok0 = (r + 0) < m, ok1 = (r + 1) < m;
        const bool ok2 = (r + 2) < m, ok3 = (r + 3) < m;
        float* q0 = agg + (size_t)d0 * H + rA;
        float* q1 = agg + (size_t)d1 * H + rA;
        float* q2 = agg + (size_t)d2 * H + rA;
        float* q3 = agg + (size_t)d3 * H + rA;
#pragma unroll
        for (int t = 0; t < 8; ++t) {
            if (ok0) atomicAdd(q0 + (t << 4), fmaxf(C[t][0] + hv0[t] + beT[t], 0.f));
            if (ok1) atomicAdd(q1 + (t << 4), fmaxf(C[t][1] + hv1[t] + beT[t], 0.f));
            if (ok2) atomicAdd(q2 + (t << 4), fmaxf(C[t][2] + hv2[t] + beT[t], 0.f));
            if (ok3) atomicAdd(q3 + (t << 4), fmaxf(C[t][3] + hv3[t] + beT[t], 0.f));
        }
    }
}

extern "C" void kernel_launch(void* const* d_in, const int* in_sizes, int n_in,
                              void* d_out, int out_size, void* d_ws, size_t ws_size,
                              hipStream_t stream) {
    const float* hN    = (const float*)d_in[0];
    const int*   ei    = (const int*)d_in[1];
    const float* ea    = (const float*)d_in[2];
    const float* valid = (const float*)d_in[3];
    const float* We    = (const float*)d_in[4];
    const float* be    = (const float*)d_in[5];
    const float* W1    = (const float*)d_in[6];
    const float* b1    = (const float*)d_in[7];
    const float* W2    = (const float*)d_in[8];
    const float* b2    = (const float*)d_in[9];
    const float* epsg  = (const float*)d_in[10];
    const float* gamma = (const float*)d_in[11];
    const float* beta  = (const float*)d_in[12];
    float* out = (float*)d_out;

    const int N = in_sizes[0] / H;
    const int E = in_sizes[1] / 2;

    // ws layout: cnt[N] | cur[N] | toff[N+1] | bsum[SCB] | bpre[SCB] |
    //            tileDst[Tcap] | tilePerm[16*Tcap]
    const int Tcap = (E + 15) / 16 + N;
    const size_t need = ((size_t)3 * N + 1 + 2 * SCB + (size_t)17 * Tcap) * sizeof(int);

    k_zero_stats<<<1, 512, 0, stream>>>();
    hipMemsetAsync(d_out, 0, (size_t)out_size * sizeof(float), stream);

    if (ws_size >= need) {
        int* cnt      = (int*)d_ws;
        int* cur      = cnt + N;
        int* toff     = cur + N;
        int* bsum     = toff + N + 1;
        int* bpre     = bsum + SCB;
        int* tileDst  = bpre + SCB;
        int* tilePerm = tileDst + Tcap;

        hipMemsetAsync(cnt, 0, (size_t)2 * N * sizeof(int), stream);
        hipMemsetAsync(tilePerm, 0xFF, (size_t)16 * Tcap * sizeof(int), stream);
        k_hist<<<2048, 256, 0, stream>>>(ei, cnt, E);
        k_scanA<<<SCB, SCT, 0, stream>>>(cnt, bsum, N);
        k_scanB<<<1, SCB, 0, stream>>>(bsum, bpre, toff + N);
        k_scanC<<<SCB, SCT, 0, stream>>>(cnt, bpre, toff, tileDst, N);
        k_fillp<<<2048, 256, 0, stream>>>(ei, toff, cur, tilePerm, E);
        k_edge_t<<<2048, 256, 0, stream>>>(hN, ei, ea, We, be, toff, tileDst,
                                           tilePerm, out, N, E);
    } else {
        k_edge_a<<<1024, 512, 0, stream>>>(hN, ei, ea, We, be, out, E);
    }

    k_mlp1<<<1024, 256, 0, stream>>>(hN, out, W1, b1, epsg, N);
    k_mlp2<<<1024, 256, 0, stream>>>(out, W2, b2, N);
    k_bnfin<<<1, 128, 0, stream>>>(gamma, beta, 1.0f / (float)N);
    k_final<<<2048, 256, 0, stream>>>(hN, valid, out, N);
}

// Round 11
// 844.621 us; speedup vs baseline: 1.5819x; 1.2728x over previous
//
#include <hip/hip_runtime.h>

#define H 128
#define ED 64
#define CH 16
#define SCB 256
#define SCT 256

typedef __attribute__((ext_vector_type(8))) short short8;
typedef __attribute__((ext_vector_type(4))) float f32x4;

// stats layout: [0:128) colsum, [128:256) colsumsq, [256:384) scale, [384:512) shift
__device__ __align__(16) float g_stats[512];

__device__ __forceinline__ unsigned short f2bf(float f) {
    unsigned u = __float_as_uint(f);
    unsigned r = u + 0x7fffu + ((u >> 16) & 1u);   // RNE
    return (unsigned short)(r >> 16);
}
__device__ __forceinline__ float bf2f(unsigned short h) {
    return __uint_as_float(((unsigned)h) << 16);
}

__global__ void k_zero_stats() {
    if (threadIdx.x < 512) g_stats[threadIdx.x] = 0.f;
}

// ================= padded-tile CSR build =================
__global__ void k_hist(const int* __restrict__ ei, int* __restrict__ cnt, int E) {
    for (int e = blockIdx.x * blockDim.x + threadIdx.x; e < E;
         e += gridDim.x * blockDim.x)
        atomicAdd(&cnt[ei[E + e]], 1);
}

__global__ __launch_bounds__(SCT) void k_scanA(const int* __restrict__ cnt,
                                               int* __restrict__ bsum, int N) {
    __shared__ int part[SCT];
    const int b = blockIdx.x, t = threadIdx.x;
    const int chunk = (N + SCB - 1) / SCB;
    const int tch = (chunk + SCT - 1) / SCT;
    const int lo = b * chunk + t * tch;
    const int hi = min(lo + tch, min((b + 1) * chunk, N));
    int s = 0;
    for (int i = lo; i < hi; ++i) s += (cnt[i] + 15) >> 4;
    part[t] = s;
    __syncthreads();
    for (int d = SCT / 2; d > 0; d >>= 1) {
        if (t < d) part[t] += part[t + d];
        __syncthreads();
    }
    if (t == 0) bsum[b] = part[0];
}

__global__ __launch_bounds__(SCB) void k_scanB(const int* __restrict__ bsum,
                                               int* __restrict__ bpre,
                                               int* __restrict__ toffN) {
    __shared__ int part[SCB];
    const int t = threadIdx.x;
    int v = bsum[t];
    part[t] = v;
    __syncthreads();
    for (int d = 1; d < SCB; d <<= 1) {
        int x = (t >= d) ? part[t - d] : 0;
        __syncthreads();
        part[t] += x;
        __syncthreads();
    }
    bpre[t] = part[t] - v;
    if (t == SCB - 1) *toffN = part[t];
}

__global__ __launch_bounds__(SCT) void k_scanC(const int* __restrict__ cnt,
                                               const int* __restrict__ bpre,
                                               int* __restrict__ toff,
                                               int* __restrict__ tileDst, int N) {
    __shared__ int part[SCT];
    const int b = blockIdx.x, t = threadIdx.x;
    const int chunk = (N + SCB - 1) / SCB;
    const int tch = (chunk + SCT - 1) / SCT;
    const int lo = b * chunk + t * tch;
    const int hi = min(lo + tch, min((b + 1) * chunk, N));
    int ls = 0;
    for (int i = lo; i < hi; ++i) ls += (cnt[i] + 15) >> 4;
    part[t] = ls;
    __syncthreads();
    for (int d = 1; d < SCT; d <<= 1) {
        int x = (t >= d) ? part[t - d] : 0;
        __syncthreads();
        part[t] += x;
        __syncthreads();
    }
    int run = bpre[b] + part[t] - ls;
    for (int i = lo; i < hi; ++i) {
        toff[i] = run;
        int c = (cnt[i] + 15) >> 4;
        for (int j = 0; j < c; ++j) tileDst[run + j] = i;
        run += c;
    }
}

__global__ void k_fillp(const int* __restrict__ ei, const int* __restrict__ toff,
                        int* __restrict__ cur, int* __restrict__ tilePerm, int E) {
    for (int e = blockIdx.x * blockDim.x + threadIdx.x; e < E;
         e += gridDim.x * blockDim.x) {
        int d = ei[E + e];
        int pos = atomicAdd(&cur[d], 1);
        int tile = toff[d] + (pos >> 4);
        tilePerm[(tile << 4) + (pos & 15)] = e;
    }
}

// ================= Edge kernel: padded tiles, reg-diet, 2-pass col-tiles =======
// A lane map: row = lane&15, k = 8*(lane>>4)+b (+32 2nd K-step)
// C/D lane map: col = lane&15, row = 4*(lane>>4)+reg   (HW-verified r5-r10)
// VGPR law on this kernel (r8/r9/r10): budget ~= 256/(waves per EU).
// This variant is dieted to ~58 live regs: C[4] 2-pass, per-t hv, be in LDS,
// streaming vlo/vhi, in-place ea rotation. Declared (256,4) -> 64-reg budget.
__global__ __launch_bounds__(256, 4) void k_edge_t(
    const float* __restrict__ hN, const int* __restrict__ ei,
    const float* __restrict__ ea, const float* __restrict__ We,
    const float* __restrict__ be, const int* __restrict__ toff,
    const int* __restrict__ tileDst, const int* __restrict__ tilePerm,
    float* __restrict__ agg, int N, int E)
{
    __shared__ __align__(16) short sBf[8][2][64][8];   // 16 KB B-fragments
    __shared__ float sBe[H];                           // 512 B bias
    const int tid = threadIdx.x;
    for (int idx = tid; idx < 8 * 2 * 64; idx += 256) {
        int t = idx >> 7, s = (idx >> 6) & 1, ll = idx & 63;
        int ra = ll & 15, kgg = ll >> 4;
        short8 f;
#pragma unroll
        for (int b = 0; b < 8; ++b) {
            int k = (s << 5) + (kgg << 3) + b;
            f[b] = (short)f2bf(We[k * H + (t << 4) + ra]);
        }
        *(short8*)&sBf[t][s][ll][0] = f;
    }
    if (tid < H) sBe[tid] = be[tid];
    const int l = tid & 63, w = tid >> 6;
    const int rA = l & 15, kg = l >> 4;
    __syncthreads();

    const int nT = toff[N];
    const int gw = (blockIdx.x << 2) | w;
    const int nW = gridDim.x << 2;
    if (gw >= nT) return;

    int peC, srcC, dstC, peN;
    float4 ea0, ea1, ea2, ea3;
    {
        peC = tilePerm[(gw << 4) + rA];
        dstC = tileDst[gw];
        srcC = (peC >= 0) ? ei[peC] : -1;
        const float* ar = ea + (size_t)max(peC, 0) * ED + (kg << 3);
        ea0 = *(const float4*)ar;        ea1 = *(const float4*)(ar + 4);
        ea2 = *(const float4*)(ar + 32); ea3 = *(const float4*)(ar + 36);
        peN = (gw + nW < nT) ? tilePerm[((gw + nW) << 4) + rA] : -1;
    }

    for (int tt = gw; tt < nT; tt += nW) {
        // 1) distribute srcs for current tile
        const int s0 = __shfl(srcC, (kg << 2) + 0);
        const int s1 = __shfl(srcC, (kg << 2) + 1);
        const int s2 = __shfl(srcC, (kg << 2) + 2);
        const int s3 = __shfl(srcC, (kg << 2) + 3);
        const float ok0 = (s0 >= 0) ? 1.f : 0.f;
        const float ok1 = (s1 >= 0) ? 1.f : 0.f;
        const float ok2 = (s2 >= 0) ? 1.f : 0.f;
        const float ok3 = (s3 >= 0) ? 1.f : 0.f;
        const size_t hb0 = (size_t)max(s0, 0) * H + rA;
        const size_t hb1 = (size_t)max(s1, 0) * H + rA;
        const size_t hb2 = (size_t)max(s2, 0) * H + rA;
        const size_t hb3 = (size_t)max(s3, 0) * H + rA;

        // 2) cvt current ea -> A frags (ea regs die here)
        short8 A0, A1;
        A0[0] = f2bf(ea0.x); A0[1] = f2bf(ea0.y); A0[2] = f2bf(ea0.z); A0[3] = f2bf(ea0.w);
        A0[4] = f2bf(ea1.x); A0[5] = f2bf(ea1.y); A0[6] = f2bf(ea1.z); A0[7] = f2bf(ea1.w);
        A1[0] = f2bf(ea2.x); A1[1] = f2bf(ea2.y); A1[2] = f2bf(ea2.z); A1[3] = f2bf(ea2.w);
        A1[4] = f2bf(ea3.x); A1[5] = f2bf(ea3.y); A1[6] = f2bf(ea3.z); A1[7] = f2bf(ea3.w);

        // 3) prefetch next tile into the freed ea regs + indices
        const int ttN = tt + nW;
        int srcN = -1, dstN = 0;
        if (ttN < nT) {
            srcN = (peN >= 0) ? ei[peN] : -1;
            dstN = tileDst[ttN];
            const float* ar = ea + (size_t)max(peN, 0) * ED + (kg << 3);
            ea0 = *(const float4*)ar;        ea1 = *(const float4*)(ar + 4);
            ea2 = *(const float4*)(ar + 32); ea3 = *(const float4*)(ar + 36);
        }
        const int ttF = tt + 2 * nW;
        const int peF = (ttF < nT) ? tilePerm[(ttF << 4) + rA] : -1;

        // 4) two passes of 4 col-tiles: MFMA (C[4]) then per-t epilogue
        float vlo = 0.f, vhi = 0.f;
#pragma unroll
        for (int pass = 0; pass < 2; ++pass) {
            f32x4 C[4];
#pragma unroll
            for (int t4 = 0; t4 < 4; ++t4) {
                const int t = (pass << 2) + t4;
                short8 b0 = *(const short8*)&sBf[t][0][l][0];
                short8 b1 = *(const short8*)&sBf[t][1][l][0];
                f32x4 c = __builtin_amdgcn_mfma_f32_16x16x32_bf16(
                    A0, b0, (f32x4){0.f, 0.f, 0.f, 0.f}, 0, 0, 0);
                C[t4] = __builtin_amdgcn_mfma_f32_16x16x32_bf16(A1, b1, c, 0, 0, 0);
            }
#pragma unroll
            for (int t4 = 0; t4 < 4; ++t4) {
                const int t = (pass << 2) + t4;
                const int co = t << 4;
                const float bb = sBe[co + rA];
                const float h0 = hN[hb0 + co];
                const float h1 = hN[hb1 + co];
                const float h2 = hN[hb2 + co];
                const float h3 = hN[hb3 + co];
                float v = fmaxf(C[t4][0] + h0 + bb, 0.f) * ok0
                        + fmaxf(C[t4][1] + h1 + bb, 0.f) * ok1
                        + fmaxf(C[t4][2] + h2 + bb, 0.f) * ok2
                        + fmaxf(C[t4][3] + h3 + bb, 0.f) * ok3;
                v += __shfl_xor(v, 16);
                v += __shfl_xor(v, 32);
                vlo = (t == kg)     ? v : vlo;
                vhi = (t == kg + 4) ? v : vhi;
            }
        }

        // 5) two coalesced atomics per tile
        float* qp = agg + (size_t)dstC * H + l;
        atomicAdd(qp, vlo);
        atomicAdd(qp + 64, vhi);

        // 6) rotate
        peC = peN; srcC = srcN; dstC = dstN; peN = peF;
    }
}

// ================= MLP layer 1 (MFMA, hi/lo activations) ======================
// 32 KB LDS, (256,3): 85-reg budget fits ~80-reg need (r10's (256,4) spilled).
__global__ __launch_bounds__(256, 3) void k_mlp1(
    const float* __restrict__ hN, float* zb, const float* __restrict__ W1,
    const float* __restrict__ b1, const float* __restrict__ epsp, int N)
{
    __shared__ __align__(16) short sBf[8][4][64][8];   // 32 KB W1 frags
    const int tid = threadIdx.x;
    for (int idx = tid; idx < 8 * 4 * 64; idx += 256) {
        int t = idx >> 8, s = (idx >> 6) & 3, ll = idx & 63;
        int ra = ll & 15, kgg = ll >> 4;
        short8 f;
#pragma unroll
        for (int b = 0; b < 8; ++b) {
            int k = (s << 5) + (kgg << 3) + b;
            f[b] = (short)f2bf(W1[k * H + (t << 4) + ra]);
        }
        *(short8*)&sBf[t][s][ll][0] = f;
    }
    __syncthreads();
    const int l = tid & 63, w = tid >> 6;
    const int rA = l & 15, kg = l >> 4;
    const float e1 = 1.f + epsp[0];
    float bT[8];
#pragma unroll
    for (int t = 0; t < 8; ++t) bT[t] = b1[(t << 4) + rA];

    const int nT = (N + CH - 1) / CH;
    for (int tt = blockIdx.x * 4 + w; tt < nT; tt += gridDim.x * 4) {
        const int n0 = tt << 4;
        const int row = min(n0 + rA, N - 1);
        const float* hrow = hN + (size_t)row * H;
        const float* arow = (const float*)zb + (size_t)row * H;
        f32x4 C[8];
#pragma unroll
        for (int t = 0; t < 8; ++t) C[t] = (f32x4){0.f, 0.f, 0.f, 0.f};

        const float* hp = hrow + (kg << 3);
        const float* ap = arow + (kg << 3);
        float4 h0 = *(const float4*)hp, h1 = *(const float4*)(hp + 4);
        float4 g0 = *(const float4*)ap, g1 = *(const float4*)(ap + 4);
#pragma unroll
        for (int s = 0; s < 4; ++s) {
            float4 h0n, h1n, g0n, g1n;
            if (s < 3) {
                const float* hp2 = hrow + ((s + 1) << 5) + (kg << 3);
                const float* ap2 = arow + ((s + 1) << 5) + (kg << 3);
                h0n = *(const float4*)hp2; h1n = *(const float4*)(hp2 + 4);
                g0n = *(const float4*)ap2; g1n = *(const float4*)(ap2 + 4);
            }
            float z[8];
            z[0] = fmaf(e1, h0.x, g0.x); z[1] = fmaf(e1, h0.y, g0.y);
            z[2] = fmaf(e1, h0.z, g0.z); z[3] = fmaf(e1, h0.w, g0.w);
            z[4] = fmaf(e1, h1.x, g1.x); z[5] = fmaf(e1, h1.y, g1.y);
            z[6] = fmaf(e1, h1.z, g1.z); z[7] = fmaf(e1, h1.w, g1.w);
            short8 ah, al;
#pragma unroll
            for (int j = 0; j < 8; ++j) {
                unsigned short hi = f2bf(z[j]);
                ah[j] = (short)hi;
                al[j] = (short)f2bf(z[j] - bf2f(hi));
            }
#pragma unroll
            for (int t = 0; t < 8; ++t) {
                short8 B = *(const short8*)&sBf[t][s][l][0];
                C[t] = __builtin_amdgcn_mfma_f32_16x16x32_bf16(ah, B, C[t], 0, 0, 0);
                C[t] = __builtin_amdgcn_mfma_f32_16x16x32_bf16(al, B, C[t], 0, 0, 0);
            }
            if (s < 3) { h0 = h0n; h1 = h1n; g0 = g0n; g1 = g1n; }
        }
#pragma unroll
        for (int t = 0; t < 8; ++t) {
#pragma unroll
            for (int rg = 0; rg < 4; ++rg) {
                int n = n0 + (kg << 2) + rg;
                float y = fmaxf(C[t][rg] + bT[t], 0.f);
                unsigned short hi = f2bf(y);
                unsigned short lo = f2bf(y - bf2f(hi));
                if (n < N)
                    ((unsigned*)zb)[(size_t)n * H + (t << 4) + rA] =
                        ((unsigned)hi << 16) | (unsigned)lo;
            }
        }
    }
}

// ================= MLP layer 2 + BN stats =================
__global__ __launch_bounds__(256, 3) void k_mlp2(
    float* zb, const float* __restrict__ W2, const float* __restrict__ b2, int N)
{
    __shared__ __align__(16) short sBf[8][4][64][8];   // 32 KB W2 frags
    const int tid = threadIdx.x;
    for (int idx = tid; idx < 8 * 4 * 64; idx += 256) {
        int t = idx >> 8, s = (idx >> 6) & 3, ll = idx & 63;
        int ra = ll & 15, kgg = ll >> 4;
        short8 f;
#pragma unroll
        for (int b = 0; b < 8; ++b) {
            int k = (s << 5) + (kgg << 3) + b;
            f[b] = (short)f2bf(W2[k * H + (t << 4) + ra]);
        }
        *(short8*)&sBf[t][s][ll][0] = f;
    }
    __syncthreads();
    const int l = tid & 63, w = tid >> 6;
    const int rA = l & 15, kg = l >> 4;
    float bT[8];
#pragma unroll
    for (int t = 0; t < 8; ++t) bT[t] = b2[(t << 4) + rA];
    float ps[8], pq[8];
#pragma unroll
    for (int t = 0; t < 8; ++t) { ps[t] = 0.f; pq[t] = 0.f; }

    const int nT = (N + CH - 1) / CH;
    for (int tt = blockIdx.x * 4 + w; tt < nT; tt += gridDim.x * 4) {
        const int n0 = tt << 4;
        const int row = min(n0 + rA, N - 1);
        const unsigned* yrow = (const unsigned*)zb + (size_t)row * H;
        f32x4 C[8];
#pragma unroll
        for (int t = 0; t < 8; ++t) C[t] = (f32x4){0.f, 0.f, 0.f, 0.f};

        const unsigned* yp = yrow + (kg << 3);
        uint4 u0 = *(const uint4*)yp, u1 = *(const uint4*)(yp + 4);
#pragma unroll
        for (int s = 0; s < 4; ++s) {
            uint4 u0n, u1n;
            if (s < 3) {
                const unsigned* yp2 = yrow + ((s + 1) << 5) + (kg << 3);
                u0n = *(const uint4*)yp2; u1n = *(const uint4*)(yp2 + 4);
            }
            short8 ah, al;
            ah[0] = (short)(u0.x >> 16); al[0] = (short)(u0.x & 0xffffu);
            ah[1] = (short)(u0.y >> 16); al[1] = (short)(u0.y & 0xffffu);
            ah[2] = (short)(u0.z >> 16); al[2] = (short)(u0.z & 0xffffu);
            ah[3] = (short)(u0.w >> 16); al[3] = (short)(u0.w & 0xffffu);
            ah[4] = (short)(u1.x >> 16); al[4] = (short)(u1.x & 0xffffu);
            ah[5] = (short)(u1.y >> 16); al[5] = (short)(u1.y & 0xffffu);
            ah[6] = (short)(u1.z >> 16); al[6] = (short)(u1.z & 0xffffu);
            ah[7] = (short)(u1.w >> 16); al[7] = (short)(u1.w & 0xffffu);
#pragma unroll
            for (int t = 0; t < 8; ++t) {
                short8 B = *(const short8*)&sBf[t][s][l][0];
                C[t] = __builtin_amdgcn_mfma_f32_16x16x32_bf16(ah, B, C[t], 0, 0, 0);
                C[t] = __builtin_amdgcn_mfma_f32_16x16x32_bf16(al, B, C[t], 0, 0, 0);
            }
            if (s < 3) { u0 = u0n; u1 = u1n; }
        }
#pragma unroll
        for (int t = 0; t < 8; ++t) {
#pragma unroll
            for (int rg = 0; rg < 4; ++rg) {
                int n = n0 + (kg << 2) + rg;
                float z2 = fmaxf(C[t][rg] + bT[t], 0.f);
                bool v = (n < N);
                if (v) ((float*)zb)[(size_t)n * H + (t << 4) + rA] = z2;
                float zc = v ? z2 : 0.f;
                ps[t] += zc;
                pq[t] += zc * zc;
            }
        }
    }
#pragma unroll
    for (int t = 0; t < 8; ++t) {
        float a = ps[t]; a += __shfl_xor(a, 16); a += __shfl_xor(a, 32); ps[t] = a;
        float b = pq[t]; b += __shfl_xor(b, 16); b += __shfl_xor(b, 32); pq[t] = b;
    }
    if (l < 16) {
#pragma unroll
        for (int t = 0; t < 8; ++t) {
            atomicAdd(&g_stats[(t << 4) + l], ps[t]);
            atomicAdd(&g_stats[128 + (t << 4) + l], pq[t]);
        }
    }
}

// ================= BN finalize =================
__global__ void k_bnfin(const float* __restrict__ gamma, const float* __restrict__ beta,
                        float invN)
{
    int t = threadIdx.x;
    float mean = g_stats[t] * invN;
    float var  = g_stats[H + t] * invN - mean * mean;
    float sc = gamma[t] * rsqrtf(var + 1e-5f);
    g_stats[256 + t] = sc;
    g_stats[384 + t] = beta[t] - mean * sc;
}

// ================= Final: out = (h + z2*scale + shift) * valid ================
__global__ void k_final(const float* __restrict__ hN, const float* __restrict__ valid,
                        float* __restrict__ out, int N)
{
    const int total = N * (H / 4);
    for (int i = blockIdx.x * blockDim.x + threadIdx.x; i < total;
         i += gridDim.x * blockDim.x) {
        int col4 = i & 31;
        int n = i >> 5;
        float4 z = ((float4*)out)[i];
        float4 hv = ((const float4*)hN)[i];
        float4 sc = *(const float4*)&g_stats[256 + col4 * 4];
        float4 sh = *(const float4*)&g_stats[384 + col4 * 4];
        float vf = valid[n];
        float4 r;
        r.x = (hv.x + fmaf(z.x, sc.x, sh.x)) * vf;
        r.y = (hv.y + fmaf(z.y, sc.y, sh.y)) * vf;
        r.z = (hv.z + fmaf(z.z, sc.z, sh.z)) * vf;
        r.w = (hv.w + fmaf(z.w, sc.w, sh.w)) * vf;
        ((float4*)out)[i] = r;
    }
}

// ================= Fallback (ws too small): natural-order atomic MFMA =========
__global__ __launch_bounds__(512, 4) void k_edge_a(
    const float* __restrict__ hN, const int* __restrict__ ei,
    const float* __restrict__ ea, const float* __restrict__ We,
    const float* __restrict__ be, float* __restrict__ agg, int E)
{
    __shared__ __align__(16) short sBf[8][2][64][8];
    const int tid = threadIdx.x;
    for (int idx = tid; idx < 8 * 2 * 64; idx += 512) {
        int t = idx >> 7, s = (idx >> 6) & 1, ll = idx & 63;
        int ra = ll & 15, kgg = ll >> 4;
        short8 f;
#pragma unroll
        for (int b = 0; b < 8; ++b) {
            int k = (s << 5) + (kgg << 3) + b;
            f[b] = (short)f2bf(We[k * H + (t << 4) + ra]);
        }
        *(short8*)&sBf[t][s][ll][0] = f;
    }
    const int l = tid & 63, w = tid >> 6;
    const int rA = l & 15, kg = l >> 4;
    float beT[8];
#pragma unroll
    for (int t = 0; t < 8; ++t) beT[t] = be[(t << 4) + rA];
    __syncthreads();

    const int nT = (E + CH - 1) / CH;
    for (int tt = (blockIdx.x << 3) | w; tt < nT; tt += gridDim.x << 3) {
        int e0 = tt * CH;
        const float* ar = ea + (size_t)min(e0 + rA, E - 1) * ED + (kg << 3);
        float4 a0 = *(const float4*)ar,        a1 = *(const float4*)(ar + 4);
        float4 a2 = *(const float4*)(ar + 32), a3 = *(const float4*)(ar + 36);
        int r0 = min(e0 + (kg << 2) + 0, E - 1), r1 = min(e0 + (kg << 2) + 1, E - 1);
        int r2 = min(e0 + (kg << 2) + 2, E - 1), r3 = min(e0 + (kg << 2) + 3, E - 1);
        int s0 = ei[r0], s1 = ei[r1], s2 = ei[r2], s3 = ei[r3];
        int d0 = ei[E + r0], d1 = ei[E + r1], d2 = ei[E + r2], d3 = ei[E + r3];
        float hv0[8], hv1[8], hv2[8], hv3[8];
        const float* hp0 = hN + (size_t)s0 * H + rA;
        const float* hp1 = hN + (size_t)s1 * H + rA;
        const float* hp2 = hN + (size_t)s2 * H + rA;
        const float* hp3 = hN + (size_t)s3 * H + rA;
#pragma unroll
        for (int t = 0; t < 8; ++t) {
            hv0[t] = hp0[t << 4]; hv1[t] = hp1[t << 4];
            hv2[t] = hp2[t << 4]; hv3[t] = hp3[t << 4];
        }
        short8 A0, A1;
        A0[0] = f2bf(a0.x); A0[1] = f2bf(a0.y); A0[2] = f2bf(a0.z); A0[3] = f2bf(a0.w);
        A0[4] = f2bf(a1.x); A0[5] = f2bf(a1.y); A0[6] = f2bf(a1.z); A0[7] = f2bf(a1.w);
        A1[0] = f2bf(a2.x); A1[1] = f2bf(a2.y); A1[2] = f2bf(a2.z); A1[3] = f2bf(a2.w);
        A1[4] = f2bf(a3.x); A1[5] = f2bf(a3.y); A1[6] = f2bf(a3.z); A1[7] = f2bf(a3.w);
        f32x4 C[8];
#pragma unroll
        for (int t = 0; t < 8; ++t) {
            short8 b0 = *(const short8*)&sBf[t][0][l][0];
            short8 b1 = *(const short8*)&sBf[t][1][l][0];
            f32x4 c = __builtin_amdgcn_mfma_f32_16x16x32_bf16(
                A0, b0, (f32x4){0.f, 0.f, 0.f, 0.f}, 0, 0, 0);
            C[t] = __builtin_amdgcn_mfma_f32_16x16x32_bf16(A1, b1, c, 0, 0, 0);
        }
        const int m = E - e0;
        const int r = kg << 2;
        const bool ok0 = (r + 0) < m, ok1 = (r + 1) < m;
        const bool ok2 = (r + 2) < m, ok3 = (r + 3) < m;
        float* q0 = agg + (size_t)d0 * H + rA;
        float* q1 = agg + (size_t)d1 * H + rA;
        float* q2 = agg + (size_t)d2 * H + rA;
        float* q3 = agg + (size_t)d3 * H + rA;
#pragma unroll
        for (int t = 0; t < 8; ++t) {
            if (ok0) atomicAdd(q0 + (t << 4), fmaxf(C[t][0] + hv0[t] + beT[t], 0.f));
            if (ok1) atomicAdd(q1 + (t << 4), fmaxf(C[t][1] + hv1[t] + beT[t], 0.f));
            if (ok2) atomicAdd(q2 + (t << 4), fmaxf(C[t][2] + hv2[t] + beT[t], 0.f));
            if (ok3) atomicAdd(q3 + (t << 4), fmaxf(C[t][3] + hv3[t] + beT[t], 0.f));
        }
    }
}

extern "C" void kernel_launch(void* const* d_in, const int* in_sizes, int n_in,
                              void* d_out, int out_size, void* d_ws, size_t ws_size,
                              hipStream_t stream) {
    const float* hN    = (const float*)d_in[0];
    const int*   ei    = (const int*)d_in[1];
    const float* ea    = (const float*)d_in[2];
    const float* valid = (const float*)d_in[3];
    const float* We    = (const float*)d_in[4];
    const float* be    = (const float*)d_in[5];
    const float* W1    = (const float*)d_in[6];
    const float* b1    = (const float*)d_in[7];
    const float* W2    = (const float*)d_in[8];
    const float* b2    = (const float*)d_in[9];
    const float* epsg  = (const float*)d_in[10];
    const float* gamma = (const float*)d_in[11];
    const float* beta  = (const float*)d_in[12];
    float* out = (float*)d_out;

    const int N = in_sizes[0] / H;
    const int E = in_sizes[1] / 2;

    // ws layout: cnt[N] | cur[N] | toff[N+1] | bsum[SCB] | bpre[SCB] |
    //            tileDst[Tcap] | tilePerm[16*Tcap]
    const int Tcap = (E + 15) / 16 + N;
    const size_t need = ((size_t)3 * N + 1 + 2 * SCB + (size_t)17 * Tcap) * sizeof(int);

    k_zero_stats<<<1, 512, 0, stream>>>();
    hipMemsetAsync(d_out, 0, (size_t)out_size * sizeof(float), stream);

    if (ws_size >= need) {
        int* cnt      = (int*)d_ws;
        int* cur      = cnt + N;
        int* toff     = cur + N;
        int* bsum     = toff + N + 1;
        int* bpre     = bsum + SCB;
        int* tileDst  = bpre + SCB;
        int* tilePerm = tileDst + Tcap;

        hipMemsetAsync(cnt, 0, (size_t)2 * N * sizeof(int), stream);
        hipMemsetAsync(tilePerm, 0xFF, (size_t)16 * Tcap * sizeof(int), stream);
        k_hist<<<2048, 256, 0, stream>>>(ei, cnt, E);
        k_scanA<<<SCB, SCT, 0, stream>>>(cnt, bsum, N);
        k_scanB<<<1, SCB, 0, stream>>>(bsum, bpre, toff + N);
        k_scanC<<<SCB, SCT, 0, stream>>>(cnt, bpre, toff, tileDst, N);
        k_fillp<<<2048, 256, 0, stream>>>(ei, toff, cur, tilePerm, E);
        k_edge_t<<<2048, 256, 0, stream>>>(hN, ei, ea, We, be, toff, tileDst,
                                           tilePerm, out, N, E);
    } else {
        k_edge_a<<<1024, 512, 0, stream>>>(hN, ei, ea, We, be, out, E);
    }

    k_mlp1<<<1024, 256, 0, stream>>>(hN, out, W1, b1, epsg, N);
    k_mlp2<<<1024, 256, 0, stream>>>(out, W2, b2, N);
    k_bnfin<<<1, 128, 0, stream>>>(gamma, beta, 1.0f / (float)N);
    k_final<<<2048, 256, 0, stream>>>(hN, valid, out, N);
}

// Round 12
// 772.240 us; speedup vs baseline: 1.7301x; 1.0937x over previous
//
#include <hip/hip_runtime.h>

#define H 128
#define ED 64
#define CH 16
#define SCB 256
#define SCT 256

typedef __attribute__((ext_vector_type(8))) short short8;
typedef __attribute__((ext_vector_type(4))) float f32x4;

// stats layout: [0:128) colsum, [128:256) colsumsq, [256:384) scale, [384:512) shift
__device__ __align__(16) float g_stats[512];

__device__ __forceinline__ unsigned short f2bf(float f) {
    unsigned u = __float_as_uint(f);
    unsigned r = u + 0x7fffu + ((u >> 16) & 1u);   // RNE
    return (unsigned short)(r >> 16);
}
__device__ __forceinline__ float bf2f(unsigned short h) {
    return __uint_as_float(((unsigned)h) << 16);
}

__global__ void k_zero_stats() {
    if (threadIdx.x < 512) g_stats[threadIdx.x] = 0.f;
}

// ================= padded-tile CSR build =================
__global__ void k_hist(const int* __restrict__ ei, int* __restrict__ cnt, int E) {
    for (int e = blockIdx.x * blockDim.x + threadIdx.x; e < E;
         e += gridDim.x * blockDim.x)
        atomicAdd(&cnt[ei[E + e]], 1);
}

__global__ __launch_bounds__(SCT) void k_scanA(const int* __restrict__ cnt,
                                               int* __restrict__ bsum, int N) {
    __shared__ int part[SCT];
    const int b = blockIdx.x, t = threadIdx.x;
    const int chunk = (N + SCB - 1) / SCB;
    const int tch = (chunk + SCT - 1) / SCT;
    const int lo = b * chunk + t * tch;
    const int hi = min(lo + tch, min((b + 1) * chunk, N));
    int s = 0;
    for (int i = lo; i < hi; ++i) s += (cnt[i] + 15) >> 4;
    part[t] = s;
    __syncthreads();
    for (int d = SCT / 2; d > 0; d >>= 1) {
        if (t < d) part[t] += part[t + d];
        __syncthreads();
    }
    if (t == 0) bsum[b] = part[0];
}

__global__ __launch_bounds__(SCB) void k_scanB(const int* __restrict__ bsum,
                                               int* __restrict__ bpre,
                                               int* __restrict__ toffN) {
    __shared__ int part[SCB];
    const int t = threadIdx.x;
    int v = bsum[t];
    part[t] = v;
    __syncthreads();
    for (int d = 1; d < SCB; d <<= 1) {
        int x = (t >= d) ? part[t - d] : 0;
        __syncthreads();
        part[t] += x;
        __syncthreads();
    }
    bpre[t] = part[t] - v;
    if (t == SCB - 1) *toffN = part[t];
}

__global__ __launch_bounds__(SCT) void k_scanC(const int* __restrict__ cnt,
                                               const int* __restrict__ bpre,
                                               int* __restrict__ toff,
                                               int* __restrict__ tileDst, int N) {
    __shared__ int part[SCT];
    const int b = blockIdx.x, t = threadIdx.x;
    const int chunk = (N + SCB - 1) / SCB;
    const int tch = (chunk + SCT - 1) / SCT;
    const int lo = b * chunk + t * tch;
    const int hi = min(lo + tch, min((b + 1) * chunk, N));
    int ls = 0;
    for (int i = lo; i < hi; ++i) ls += (cnt[i] + 15) >> 4;
    part[t] = ls;
    __syncthreads();
    for (int d = 1; d < SCT; d <<= 1) {
        int x = (t >= d) ? part[t - d] : 0;
        __syncthreads();
        part[t] += x;
        __syncthreads();
    }
    int run = bpre[b] + part[t] - ls;
    for (int i = lo; i < hi; ++i) {
        toff[i] = run;
        int c = (cnt[i] + 15) >> 4;
        for (int j = 0; j < c; ++j) tileDst[run + j] = i;
        run += c;
    }
}

__global__ void k_fillp(const int* __restrict__ ei, const int* __restrict__ toff,
                        int* __restrict__ cur, int* __restrict__ tilePerm, int E) {
    for (int e = blockIdx.x * blockDim.x + threadIdx.x; e < E;
         e += gridDim.x * blockDim.x) {
        int d = ei[E + e];
        int pos = atomicAdd(&cur[d], 1);
        int tile = toff[d] + (pos >> 4);
        tilePerm[(tile << 4) + (pos & 15)] = e;
    }
}

// ================= Edge kernel: r8-verbatim (proven 268 us, no spill) ==========
// A lane map: row = lane&15, k = 8*(lane>>4)+b (+32 2nd K-step)
// C/D lane map: col = lane&15, row = 4*(lane>>4)+reg   (HW-verified r5-r11)
// (256,3): ~84 live VGPR fits the 85 budget. r9(48) and r11(64) both spilled;
// this kernel's footprint is ~84 -> 3 waves/EU is its occupancy optimum.
__global__ __launch_bounds__(256, 3) void k_edge_t(
    const float* __restrict__ hN, const int* __restrict__ ei,
    const float* __restrict__ ea, const float* __restrict__ We,
    const float* __restrict__ be, const int* __restrict__ toff,
    const int* __restrict__ tileDst, const int* __restrict__ tilePerm,
    float* __restrict__ agg, int N, int E)
{
    __shared__ __align__(16) short sBf[8][2][64][8];   // 16 KB B-fragments
    const int tid = threadIdx.x;
    for (int idx = tid; idx < 8 * 2 * 64; idx += 256) {
        int t = idx >> 7, s = (idx >> 6) & 1, ll = idx & 63;
        int ra = ll & 15, kgg = ll >> 4;
        short8 f;
#pragma unroll
        for (int b = 0; b < 8; ++b) {
            int k = (s << 5) + (kgg << 3) + b;
            f[b] = (short)f2bf(We[k * H + (t << 4) + ra]);
        }
        *(short8*)&sBf[t][s][ll][0] = f;
    }
    const int l = tid & 63, w = tid >> 6;
    const int rA = l & 15, kg = l >> 4;
    float beT[8];
#pragma unroll
    for (int t = 0; t < 8; ++t) beT[t] = be[(t << 4) + rA];
    __syncthreads();

    const int nT = toff[N];
    const int gw = (blockIdx.x << 2) | w;
    const int nW = gridDim.x << 2;
    if (gw >= nT) return;

    int peC, srcC, dstC;
    float4 ea0, ea1, ea2, ea3;
    int peN;
    {
        peC = tilePerm[(gw << 4) + rA];
        dstC = tileDst[gw];
        srcC = (peC >= 0) ? ei[peC] : -1;
        const float* ar = ea + (size_t)max(peC, 0) * ED + (kg << 3);
        ea0 = *(const float4*)ar;        ea1 = *(const float4*)(ar + 4);
        ea2 = *(const float4*)(ar + 32); ea3 = *(const float4*)(ar + 36);
        peN = (gw + nW < nT) ? tilePerm[((gw + nW) << 4) + rA] : -1;
    }

    for (int tt = gw; tt < nT; tt += nW) {
        // 1) distribute srcs, issue hv gathers
        const int s0 = __shfl(srcC, (kg << 2) + 0);
        const int s1 = __shfl(srcC, (kg << 2) + 1);
        const int s2 = __shfl(srcC, (kg << 2) + 2);
        const int s3 = __shfl(srcC, (kg << 2) + 3);
        float hv0[8], hv1[8], hv2[8], hv3[8];
        {
            const float* hp0 = hN + (size_t)max(s0, 0) * H + rA;
            const float* hp1 = hN + (size_t)max(s1, 0) * H + rA;
            const float* hp2 = hN + (size_t)max(s2, 0) * H + rA;
            const float* hp3 = hN + (size_t)max(s3, 0) * H + rA;
#pragma unroll
            for (int t = 0; t < 8; ++t) {
                hv0[t] = hp0[t << 4]; hv1[t] = hp1[t << 4];
                hv2[t] = hp2[t << 4]; hv3[t] = hp3[t << 4];
            }
        }
        // 2) next tile's src/dst/ea via peN
        const int ttN = tt + nW;
        int srcN = -1, dstN = 0;
        float4 eb0, eb1, eb2, eb3;
        eb0 = eb1 = eb2 = eb3 = make_float4(0.f, 0.f, 0.f, 0.f);
        if (ttN < nT) {
            srcN = (peN >= 0) ? ei[peN] : -1;
            dstN = tileDst[ttN];
            const float* ar = ea + (size_t)max(peN, 0) * ED + (kg << 3);
            eb0 = *(const float4*)ar;        eb1 = *(const float4*)(ar + 4);
            eb2 = *(const float4*)(ar + 32); eb3 = *(const float4*)(ar + 36);
        }
        // 3) depth-2 linear perm prefetch
        const int ttF = tt + 2 * nW;
        const int peF = (ttF < nT) ? tilePerm[(ttF << 4) + rA] : -1;

        // 4) cvt A -> bf16, 16 MFMAs
        short8 A0, A1;
        A0[0] = f2bf(ea0.x); A0[1] = f2bf(ea0.y); A0[2] = f2bf(ea0.z); A0[3] = f2bf(ea0.w);
        A0[4] = f2bf(ea1.x); A0[5] = f2bf(ea1.y); A0[6] = f2bf(ea1.z); A0[7] = f2bf(ea1.w);
        A1[0] = f2bf(ea2.x); A1[1] = f2bf(ea2.y); A1[2] = f2bf(ea2.z); A1[3] = f2bf(ea2.w);
        A1[4] = f2bf(ea3.x); A1[5] = f2bf(ea3.y); A1[6] = f2bf(ea3.z); A1[7] = f2bf(ea3.w);
        f32x4 C[8];
#pragma unroll
        for (int t = 0; t < 8; ++t) {
            short8 b0 = *(const short8*)&sBf[t][0][l][0];
            short8 b1 = *(const short8*)&sBf[t][1][l][0];
            f32x4 c = __builtin_amdgcn_mfma_f32_16x16x32_bf16(
                A0, b0, (f32x4){0.f, 0.f, 0.f, 0.f}, 0, 0, 0);
            C[t] = __builtin_amdgcn_mfma_f32_16x16x32_bf16(A1, b1, c, 0, 0, 0);
        }

        // 5) epilogue: relu(msg + h + be), column reduce, 2 atomics
        const float ok0 = (s0 >= 0) ? 1.f : 0.f;
        const float ok1 = (s1 >= 0) ? 1.f : 0.f;
        const float ok2 = (s2 >= 0) ? 1.f : 0.f;
        const float ok3 = (s3 >= 0) ? 1.f : 0.f;
        float pacc[8];
#pragma unroll
        for (int t = 0; t < 8; ++t) {
            float v = fmaxf(C[t][0] + hv0[t] + beT[t], 0.f) * ok0
                    + fmaxf(C[t][1] + hv1[t] + beT[t], 0.f) * ok1
                    + fmaxf(C[t][2] + hv2[t] + beT[t], 0.f) * ok2
                    + fmaxf(C[t][3] + hv3[t] + beT[t], 0.f) * ok3;
            v += __shfl_xor(v, 16);
            v += __shfl_xor(v, 32);
            pacc[t] = v;
        }
        float vlo = (kg == 0) ? pacc[0] : (kg == 1) ? pacc[1] : (kg == 2) ? pacc[2] : pacc[3];
        float vhi = (kg == 0) ? pacc[4] : (kg == 1) ? pacc[5] : (kg == 2) ? pacc[6] : pacc[7];
        float* qp = agg + (size_t)dstC * H + l;
        atomicAdd(qp, vlo);
        atomicAdd(qp + 64, vhi);

        peC = peN; srcC = srcN; dstC = dstN;
        ea0 = eb0; ea1 = eb1; ea2 = eb2; ea3 = eb3;
        peN = peF;
    }
}

// ================= MLP layer 1 (MFMA, hi/lo activations, reg-dieted) ==========
// No h/g prefetch (that was +32 regs -> silent spill at the 85 budget).
// Peak live ~70 VGPR; (256,3) fits cleanly; TLP + MFMA hide the L2 latency.
__global__ __launch_bounds__(256, 3) void k_mlp1(
    const float* __restrict__ hN, float* zb, const float* __restrict__ W1,
    const float* __restrict__ b1, const float* __restrict__ epsp, int N)
{
    __shared__ __align__(16) short sBf[8][4][64][8];   // 32 KB W1 frags
    const int tid = threadIdx.x;
    for (int idx = tid; idx < 8 * 4 * 64; idx += 256) {
        int t = idx >> 8, s = (idx >> 6) & 3, ll = idx & 63;
        int ra = ll & 15, kgg = ll >> 4;
        short8 f;
#pragma unroll
        for (int b = 0; b < 8; ++b) {
            int k = (s << 5) + (kgg << 3) + b;
            f[b] = (short)f2bf(W1[k * H + (t << 4) + ra]);
        }
        *(short8*)&sBf[t][s][ll][0] = f;
    }
    __syncthreads();
    const int l = tid & 63, w = tid >> 6;
    const int rA = l & 15, kg = l >> 4;
    const float e1 = 1.f + epsp[0];
    float bT[8];
#pragma unroll
    for (int t = 0; t < 8; ++t) bT[t] = b1[(t << 4) + rA];

    const int nT = (N + CH - 1) / CH;
    for (int tt = blockIdx.x * 4 + w; tt < nT; tt += gridDim.x * 4) {
        const int n0 = tt << 4;
        const int row = min(n0 + rA, N - 1);
        const float* hrow = hN + (size_t)row * H;
        const float* arow = (const float*)zb + (size_t)row * H;
        f32x4 C[8];
#pragma unroll
        for (int t = 0; t < 8; ++t) C[t] = (f32x4){0.f, 0.f, 0.f, 0.f};

#pragma unroll
        for (int s = 0; s < 4; ++s) {
            const float* hp = hrow + (s << 5) + (kg << 3);
            const float* ap = arow + (s << 5) + (kg << 3);
            float4 h0 = *(const float4*)hp, h1 = *(const float4*)(hp + 4);
            float4 g0 = *(const float4*)ap, g1 = *(const float4*)(ap + 4);
            float z[8];
            z[0] = fmaf(e1, h0.x, g0.x); z[1] = fmaf(e1, h0.y, g0.y);
            z[2] = fmaf(e1, h0.z, g0.z); z[3] = fmaf(e1, h0.w, g0.w);
            z[4] = fmaf(e1, h1.x, g1.x); z[5] = fmaf(e1, h1.y, g1.y);
            z[6] = fmaf(e1, h1.z, g1.z); z[7] = fmaf(e1, h1.w, g1.w);
            short8 ah, al;
#pragma unroll
            for (int j = 0; j < 8; ++j) {
                unsigned short hi = f2bf(z[j]);
                ah[j] = (short)hi;
                al[j] = (short)f2bf(z[j] - bf2f(hi));
            }
#pragma unroll
            for (int t = 0; t < 8; ++t) {
                short8 B = *(const short8*)&sBf[t][s][l][0];
                C[t] = __builtin_amdgcn_mfma_f32_16x16x32_bf16(ah, B, C[t], 0, 0, 0);
                C[t] = __builtin_amdgcn_mfma_f32_16x16x32_bf16(al, B, C[t], 0, 0, 0);
            }
        }
#pragma unroll
        for (int t = 0; t < 8; ++t) {
#pragma unroll
            for (int rg = 0; rg < 4; ++rg) {
                int n = n0 + (kg << 2) + rg;
                float y = fmaxf(C[t][rg] + bT[t], 0.f);
                unsigned short hi = f2bf(y);
                unsigned short lo = f2bf(y - bf2f(hi));
                if (n < N)
                    ((unsigned*)zb)[(size_t)n * H + (t << 4) + rA] =
                        ((unsigned)hi << 16) | (unsigned)lo;
            }
        }
    }
}

// ================= MLP layer 2 + BN stats (reg-dieted, no prefetch) ===========
__global__ __launch_bounds__(256, 3) void k_mlp2(
    float* zb, const float* __restrict__ W2, const float* __restrict__ b2, int N)
{
    __shared__ __align__(16) short sBf[8][4][64][8];   // 32 KB W2 frags
    const int tid = threadIdx.x;
    for (int idx = tid; idx < 8 * 4 * 64; idx += 256) {
        int t = idx >> 8, s = (idx >> 6) & 3, ll = idx & 63;
        int ra = ll & 15, kgg = ll >> 4;
        short8 f;
#pragma unroll
        for (int b = 0; b < 8; ++b) {
            int k = (s << 5) + (kgg << 3) + b;
            f[b] = (short)f2bf(W2[k * H + (t << 4) + ra]);
        }
        *(short8*)&sBf[t][s][ll][0] = f;
    }
    __syncthreads();
    const int l = tid & 63, w = tid >> 6;
    const int rA = l & 15, kg = l >> 4;
    float bT[8];
#pragma unroll
    for (int t = 0; t < 8; ++t) bT[t] = b2[(t << 4) + rA];
    float ps[8], pq[8];
#pragma unroll
    for (int t = 0; t < 8; ++t) { ps[t] = 0.f; pq[t] = 0.f; }

    const int nT = (N + CH - 1) / CH;
    for (int tt = blockIdx.x * 4 + w; tt < nT; tt += gridDim.x * 4) {
        const int n0 = tt << 4;
        const int row = min(n0 + rA, N - 1);
        const unsigned* yrow = (const unsigned*)zb + (size_t)row * H;
        f32x4 C[8];
#pragma unroll
        for (int t = 0; t < 8; ++t) C[t] = (f32x4){0.f, 0.f, 0.f, 0.f};

#pragma unroll
        for (int s = 0; s < 4; ++s) {
            const unsigned* yp = yrow + (s << 5) + (kg << 3);
            uint4 u0 = *(const uint4*)yp, u1 = *(const uint4*)(yp + 4);
            short8 ah, al;
            ah[0] = (short)(u0.x >> 16); al[0] = (short)(u0.x & 0xffffu);
            ah[1] = (short)(u0.y >> 16); al[1] = (short)(u0.y & 0xffffu);
            ah[2] = (short)(u0.z >> 16); al[2] = (short)(u0.z & 0xffffu);
            ah[3] = (short)(u0.w >> 16); al[3] = (short)(u0.w & 0xffffu);
            ah[4] = (short)(u1.x >> 16); al[4] = (short)(u1.x & 0xffffu);
            ah[5] = (short)(u1.y >> 16); al[5] = (short)(u1.y & 0xffffu);
            ah[6] = (short)(u1.z >> 16); al[6] = (short)(u1.z & 0xffffu);
            ah[7] = (short)(u1.w >> 16); al[7] = (short)(u1.w & 0xffffu);
#pragma unroll
            for (int t = 0; t < 8; ++t) {
                short8 B = *(const short8*)&sBf[t][s][l][0];
                C[t] = __builtin_amdgcn_mfma_f32_16x16x32_bf16(ah, B, C[t], 0, 0, 0);
                C[t] = __builtin_amdgcn_mfma_f32_16x16x32_bf16(al, B, C[t], 0, 0, 0);
            }
        }
#pragma unroll
        for (int t = 0; t < 8; ++t) {
#pragma unroll
            for (int rg = 0; rg < 4; ++rg) {
                int n = n0 + (kg << 2) + rg;
                float z2 = fmaxf(C[t][rg] + bT[t], 0.f);
                bool v = (n < N);
                if (v) ((float*)zb)[(size_t)n * H + (t << 4) + rA] = z2;
                float zc = v ? z2 : 0.f;
                ps[t] += zc;
                pq[t] += zc * zc;
            }
        }
    }
#pragma unroll
    for (int t = 0; t < 8; ++t) {
        float a = ps[t]; a += __shfl_xor(a, 16); a += __shfl_xor(a, 32); ps[t] = a;
        float b = pq[t]; b += __shfl_xor(b, 16); b += __shfl_xor(b, 32); pq[t] = b;
    }
    if (l < 16) {
#pragma unroll
        for (int t = 0; t < 8; ++t) {
            atomicAdd(&g_stats[(t << 4) + l], ps[t]);
            atomicAdd(&g_stats[128 + (t << 4) + l], pq[t]);
        }
    }
}

// ================= BN finalize =================
__global__ void k_bnfin(const float* __restrict__ gamma, const float* __restrict__ beta,
                        float invN)
{
    int t = threadIdx.x;
    float mean = g_stats[t] * invN;
    float var  = g_stats[H + t] * invN - mean * mean;
    float sc = gamma[t] * rsqrtf(var + 1e-5f);
    g_stats[256 + t] = sc;
    g_stats[384 + t] = beta[t] - mean * sc;
}

// ================= Final: out = (h + z2*scale + shift) * valid ================
__global__ void k_final(const float* __restrict__ hN, const float* __restrict__ valid,
                        float* __restrict__ out, int N)
{
    const int total = N * (H / 4);
    for (int i = blockIdx.x * blockDim.x + threadIdx.x; i < total;
         i += gridDim.x * blockDim.x) {
        int col4 = i & 31;
        int n = i >> 5;
        float4 z = ((float4*)out)[i];
        float4 hv = ((const float4*)hN)[i];
        float4 sc = *(const float4*)&g_stats[256 + col4 * 4];
        float4 sh = *(const float4*)&g_stats[384 + col4 * 4];
        float vf = valid[n];
        float4 r;
        r.x = (hv.x + fmaf(z.x, sc.x, sh.x)) * vf;
        r.y = (hv.y + fmaf(z.y, sc.y, sh.y)) * vf;
        r.z = (hv.z + fmaf(z.z, sc.z, sh.z)) * vf;
        r.w = (hv.w + fmaf(z.w, sc.w, sh.w)) * vf;
        ((float4*)out)[i] = r;
    }
}

// ================= Fallback (ws too small): natural-order atomic MFMA =========
__global__ __launch_bounds__(512, 4) void k_edge_a(
    const float* __restrict__ hN, const int* __restrict__ ei,
    const float* __restrict__ ea, const float* __restrict__ We,
    const float* __restrict__ be, float* __restrict__ agg, int E)
{
    __shared__ __align__(16) short sBf[8][2][64][8];
    const int tid = threadIdx.x;
    for (int idx = tid; idx < 8 * 2 * 64; idx += 512) {
        int t = idx >> 7, s = (idx >> 6) & 1, ll = idx & 63;
        int ra = ll & 15, kgg = ll >> 4;
        short8 f;
#pragma unroll
        for (int b = 0; b < 8; ++b) {
            int k = (s << 5) + (kgg << 3) + b;
            f[b] = (short)f2bf(We[k * H + (t << 4) + ra]);
        }
        *(short8*)&sBf[t][s][ll][0] = f;
    }
    const int l = tid & 63, w = tid >> 6;
    const int rA = l & 15, kg = l >> 4;
    float beT[8];
#pragma unroll
    for (int t = 0; t < 8; ++t) beT[t] = be[(t << 4) + rA];
    __syncthreads();

    const int nT = (E + CH - 1) / CH;
    for (int tt = (blockIdx.x << 3) | w; tt < nT; tt += gridDim.x << 3) {
        int e0 = tt * CH;
        const float* ar = ea + (size_t)min(e0 + rA, E - 1) * ED + (kg << 3);
        float4 a0 = *(const float4*)ar,        a1 = *(const float4*)(ar + 4);
        float4 a2 = *(const float4*)(ar + 32), a3 = *(const float4*)(ar + 36);
        int r0 = min(e0 + (kg << 2) + 0, E - 1), r1 = min(e0 + (kg << 2) + 1, E - 1);
        int r2 = min(e0 + (kg << 2) + 2, E - 1), r3 = min(e0 + (kg << 2) + 3, E - 1);
        int s0 = ei[r0], s1 = ei[r1], s2 = ei[r2], s3 = ei[r3];
        int d0 = ei[E + r0], d1 = ei[E + r1], d2 = ei[E + r2], d3 = ei[E + r3];
        float hv0[8], hv1[8], hv2[8], hv3[8];
        const float* hp0 = hN + (size_t)s0 * H + rA;
        const float* hp1 = hN + (size_t)s1 * H + rA;
        const float* hp2 = hN + (size_t)s2 * H + rA;
        const float* hp3 = hN + (size_t)s3 * H + rA;
#pragma unroll
        for (int t = 0; t < 8; ++t) {
            hv0[t] = hp0[t << 4]; hv1[t] = hp1[t << 4];
            hv2[t] = hp2[t << 4]; hv3[t] = hp3[t << 4];
        }
        short8 A0, A1;
        A0[0] = f2bf(a0.x); A0[1] = f2bf(a0.y); A0[2] = f2bf(a0.z); A0[3] = f2bf(a0.w);
        A0[4] = f2bf(a1.x); A0[5] = f2bf(a1.y); A0[6] = f2bf(a1.z); A0[7] = f2bf(a1.w);
        A1[0] = f2bf(a2.x); A1[1] = f2bf(a2.y); A1[2] = f2bf(a2.z); A1[3] = f2bf(a2.w);
        A1[4] = f2bf(a3.x); A1[5] = f2bf(a3.y); A1[6] = f2bf(a3.z); A1[7] = f2bf(a3.w);
        f32x4 C[8];
#pragma unroll
        for (int t = 0; t < 8; ++t) {
            short8 b0 = *(const short8*)&sBf[t][0][l][0];
            short8 b1 = *(const short8*)&sBf[t][1][l][0];
            f32x4 c = __builtin_amdgcn_mfma_f32_16x16x32_bf16(
                A0, b0, (f32x4){0.f, 0.f, 0.f, 0.f}, 0, 0, 0);
            C[t] = __builtin_amdgcn_mfma_f32_16x16x32_bf16(A1, b1, c, 0, 0, 0);
        }
        const int m = E - e0;
        const int r = kg << 2;
        const bool ok0 = (r + 0) < m, ok1 = (r + 1) < m;
        const bool ok2 = (r + 2) < m, ok3 = (r + 3) < m;
        float* q0 = agg + (size_t)d0 * H + rA;
        float* q1 = agg + (size_t)d1 * H + rA;
        float* q2 = agg + (size_t)d2 * H + rA;
        float* q3 = agg + (size_t)d3 * H + rA;
#pragma unroll
        for (int t = 0; t < 8; ++t) {
            if (ok0) atomicAdd(q0 + (t << 4), fmaxf(C[t][0] + hv0[t] + beT[t], 0.f));
            if (ok1) atomicAdd(q1 + (t << 4), fmaxf(C[t][1] + hv1[t] + beT[t], 0.f));
            if (ok2) atomicAdd(q2 + (t << 4), fmaxf(C[t][2] + hv2[t] + beT[t], 0.f));
            if (ok3) atomicAdd(q3 + (t << 4), fmaxf(C[t][3] + hv3[t] + beT[t], 0.f));
        }
    }
}

extern "C" void kernel_launch(void* const* d_in, const int* in_sizes, int n_in,
                              void* d_out, int out_size, void* d_ws, size_t ws_size,
                              hipStream_t stream) {
    const float* hN    = (const float*)d_in[0];
    const int*   ei    = (const int*)d_in[1];
    const float* ea    = (const float*)d_in[2];
    const float* valid = (const float*)d_in[3];
    const float* We    = (const float*)d_in[4];
    const float* be    = (const float*)d_in[5];
    const float* W1    = (const float*)d_in[6];
    const float* b1    = (const float*)d_in[7];
    const float* W2    = (const float*)d_in[8];
    const float* b2    = (const float*)d_in[9];
    const float* epsg  = (const float*)d_in[10];
    const float* gamma = (const float*)d_in[11];
    const float* beta  = (const float*)d_in[12];
    float* out = (float*)d_out;

    const int N = in_sizes[0] / H;
    const int E = in_sizes[1] / 2;

    // ws layout: cnt[N] | cur[N] | toff[N+1] | bsum[SCB] | bpre[SCB] |
    //            tileDst[Tcap] | tilePerm[16*Tcap]
    const int Tcap = (E + 15) / 16 + N;
    const size_t need = ((size_t)3 * N + 1 + 2 * SCB + (size_t)17 * Tcap) * sizeof(int);

    k_zero_stats<<<1, 512, 0, stream>>>();
    hipMemsetAsync(d_out, 0, (size_t)out_size * sizeof(float), stream);

    if (ws_size >= need) {
        int* cnt      = (int*)d_ws;
        int* cur      = cnt + N;
        int* toff     = cur + N;
        int* bsum     = toff + N + 1;
        int* bpre     = bsum + SCB;
        int* tileDst  = bpre + SCB;
        int* tilePerm = tileDst + Tcap;

        hipMemsetAsync(cnt, 0, (size_t)2 * N * sizeof(int), stream);
        hipMemsetAsync(tilePerm, 0xFF, (size_t)16 * Tcap * sizeof(int), stream);
        k_hist<<<2048, 256, 0, stream>>>(ei, cnt, E);
        k_scanA<<<SCB, SCT, 0, stream>>>(cnt, bsum, N);
        k_scanB<<<1, SCB, 0, stream>>>(bsum, bpre, toff + N);
        k_scanC<<<SCB, SCT, 0, stream>>>(cnt, bpre, toff, tileDst, N);
        k_fillp<<<2048, 256, 0, stream>>>(ei, toff, cur, tilePerm, E);
        k_edge_t<<<2048, 256, 0, stream>>>(hN, ei, ea, We, be, toff, tileDst,
                                           tilePerm, out, N, E);
    } else {
        k_edge_a<<<1024, 512, 0, stream>>>(hN, ei, ea, We, be, out, E);
    }

    k_mlp1<<<1024, 256, 0, stream>>>(hN, out, W1, b1, epsg, N);
    k_mlp2<<<1024, 256, 0, stream>>>(out, W2, b2, N);
    k_bnfin<<<1, 128, 0, stream>>>(gamma, beta, 1.0f / (float)N);
    k_final<<<2048, 256, 0, stream>>>(hN, valid, out, N);
}

// Round 13
// 622.750 us; speedup vs baseline: 2.1455x; 1.2400x over previous
//
#include <hip/hip_runtime.h>

#define H 128
#define ED 64
#define CH 16
#define SCB 256
#define SCT 256

typedef __attribute__((ext_vector_type(8))) short short8;
typedef __attribute__((ext_vector_type(4))) float f32x4;

// stats layout: [0:128) colsum, [128:256) colsumsq
__device__ __align__(16) float g_stats[256];

__device__ __forceinline__ unsigned short f2bf(float f) {
    unsigned u = __float_as_uint(f);
    unsigned r = u + 0x7fffu + ((u >> 16) & 1u);   // RNE
    return (unsigned short)(r >> 16);
}
__device__ __forceinline__ float bf2f(unsigned short h) {
    return __uint_as_float(((unsigned)h) << 16);
}

__global__ void k_zero_stats() {
    if (threadIdx.x < 256) g_stats[threadIdx.x] = 0.f;
}

// ================= padded-tile CSR build =================
// block 0 also zeroes g_stats (folded k_zero_stats; saves a launch)
__global__ void k_hist(const int* __restrict__ ei, int* __restrict__ cnt, int E) {
    if (blockIdx.x == 0 && threadIdx.x < 256) g_stats[threadIdx.x] = 0.f;
    for (int e = blockIdx.x * blockDim.x + threadIdx.x; e < E;
         e += gridDim.x * blockDim.x)
        atomicAdd(&cnt[ei[E + e]], 1);
}

__global__ __launch_bounds__(SCT) void k_scanA(const int* __restrict__ cnt,
                                               int* __restrict__ bsum, int N) {
    __shared__ int part[SCT];
    const int b = blockIdx.x, t = threadIdx.x;
    const int chunk = (N + SCB - 1) / SCB;
    const int tch = (chunk + SCT - 1) / SCT;
    const int lo = b * chunk + t * tch;
    const int hi = min(lo + tch, min((b + 1) * chunk, N));
    int s = 0;
    for (int i = lo; i < hi; ++i) s += (cnt[i] + 15) >> 4;
    part[t] = s;
    __syncthreads();
    for (int d = SCT / 2; d > 0; d >>= 1) {
        if (t < d) part[t] += part[t + d];
        __syncthreads();
    }
    if (t == 0) bsum[b] = part[0];
}

__global__ __launch_bounds__(SCB) void k_scanB(const int* __restrict__ bsum,
                                               int* __restrict__ bpre,
                                               int* __restrict__ toffN) {
    __shared__ int part[SCB];
    const int t = threadIdx.x;
    int v = bsum[t];
    part[t] = v;
    __syncthreads();
    for (int d = 1; d < SCB; d <<= 1) {
        int x = (t >= d) ? part[t - d] : 0;
        __syncthreads();
        part[t] += x;
        __syncthreads();
    }
    bpre[t] = part[t] - v;
    if (t == SCB - 1) *toffN = part[t];
}

__global__ __launch_bounds__(SCT) void k_scanC(const int* __restrict__ cnt,
                                               const int* __restrict__ bpre,
                                               int* __restrict__ toff,
                                               int* __restrict__ tileDst, int N) {
    __shared__ int part[SCT];
    const int b = blockIdx.x, t = threadIdx.x;
    const int chunk = (N + SCB - 1) / SCB;
    const int tch = (chunk + SCT - 1) / SCT;
    const int lo = b * chunk + t * tch;
    const int hi = min(lo + tch, min((b + 1) * chunk, N));
    int ls = 0;
    for (int i = lo; i < hi; ++i) ls += (cnt[i] + 15) >> 4;
    part[t] = ls;
    __syncthreads();
    for (int d = 1; d < SCT; d <<= 1) {
        int x = (t >= d) ? part[t - d] : 0;
        __syncthreads();
        part[t] += x;
        __syncthreads();
    }
    int run = bpre[b] + part[t] - ls;
    for (int i = lo; i < hi; ++i) {
        toff[i] = run;
        int c = (cnt[i] + 15) >> 4;
        for (int j = 0; j < c; ++j) tileDst[run + j] = i;
        run += c;
    }
}

__global__ void k_fillp(const int* __restrict__ ei, const int* __restrict__ toff,
                        int* __restrict__ cur, int* __restrict__ tilePerm, int E) {
    for (int e = blockIdx.x * blockDim.x + threadIdx.x; e < E;
         e += gridDim.x * blockDim.x) {
        int d = ei[E + e];
        int pos = atomicAdd(&cur[d], 1);
        int tile = toff[d] + (pos >> 4);
        tilePerm[(tile << 4) + (pos & 15)] = e;
    }
}

// ================= Edge kernel: r8-verbatim (proven 268 us, no spill) ==========
// A lane map: row = lane&15, k = 8*(lane>>4)+b (+32 2nd K-step)
// C/D lane map: col = lane&15, row = 4*(lane>>4)+reg   (HW-verified r5-r12)
// (256,3): 85-reg budget, uses 84 (measured r12) -> no spill. Edge optimum.
__global__ __launch_bounds__(256, 3) void k_edge_t(
    const float* __restrict__ hN, const int* __restrict__ ei,
    const float* __restrict__ ea, const float* __restrict__ We,
    const float* __restrict__ be, const int* __restrict__ toff,
    const int* __restrict__ tileDst, const int* __restrict__ tilePerm,
    float* __restrict__ agg, int N, int E)
{
    __shared__ __align__(16) short sBf[8][2][64][8];   // 16 KB B-fragments
    const int tid = threadIdx.x;
    for (int idx = tid; idx < 8 * 2 * 64; idx += 256) {
        int t = idx >> 7, s = (idx >> 6) & 1, ll = idx & 63;
        int ra = ll & 15, kgg = ll >> 4;
        short8 f;
#pragma unroll
        for (int b = 0; b < 8; ++b) {
            int k = (s << 5) + (kgg << 3) + b;
            f[b] = (short)f2bf(We[k * H + (t << 4) + ra]);
        }
        *(short8*)&sBf[t][s][ll][0] = f;
    }
    const int l = tid & 63, w = tid >> 6;
    const int rA = l & 15, kg = l >> 4;
    float beT[8];
#pragma unroll
    for (int t = 0; t < 8; ++t) beT[t] = be[(t << 4) + rA];
    __syncthreads();

    const int nT = toff[N];
    const int gw = (blockIdx.x << 2) | w;
    const int nW = gridDim.x << 2;
    if (gw >= nT) return;

    int peC, srcC, dstC;
    float4 ea0, ea1, ea2, ea3;
    int peN;
    {
        peC = tilePerm[(gw << 4) + rA];
        dstC = tileDst[gw];
        srcC = (peC >= 0) ? ei[peC] : -1;
        const float* ar = ea + (size_t)max(peC, 0) * ED + (kg << 3);
        ea0 = *(const float4*)ar;        ea1 = *(const float4*)(ar + 4);
        ea2 = *(const float4*)(ar + 32); ea3 = *(const float4*)(ar + 36);
        peN = (gw + nW < nT) ? tilePerm[((gw + nW) << 4) + rA] : -1;
    }

    for (int tt = gw; tt < nT; tt += nW) {
        // 1) distribute srcs, issue hv gathers
        const int s0 = __shfl(srcC, (kg << 2) + 0);
        const int s1 = __shfl(srcC, (kg << 2) + 1);
        const int s2 = __shfl(srcC, (kg << 2) + 2);
        const int s3 = __shfl(srcC, (kg << 2) + 3);
        float hv0[8], hv1[8], hv2[8], hv3[8];
        {
            const float* hp0 = hN + (size_t)max(s0, 0) * H + rA;
            const float* hp1 = hN + (size_t)max(s1, 0) * H + rA;
            const float* hp2 = hN + (size_t)max(s2, 0) * H + rA;
            const float* hp3 = hN + (size_t)max(s3, 0) * H + rA;
#pragma unroll
            for (int t = 0; t < 8; ++t) {
                hv0[t] = hp0[t << 4]; hv1[t] = hp1[t << 4];
                hv2[t] = hp2[t << 4]; hv3[t] = hp3[t << 4];
            }
        }
        // 2) next tile's src/dst/ea via peN
        const int ttN = tt + nW;
        int srcN = -1, dstN = 0;
        float4 eb0, eb1, eb2, eb3;
        eb0 = eb1 = eb2 = eb3 = make_float4(0.f, 0.f, 0.f, 0.f);
        if (ttN < nT) {
            srcN = (peN >= 0) ? ei[peN] : -1;
            dstN = tileDst[ttN];
            const float* ar = ea + (size_t)max(peN, 0) * ED + (kg << 3);
            eb0 = *(const float4*)ar;        eb1 = *(const float4*)(ar + 4);
            eb2 = *(const float4*)(ar + 32); eb3 = *(const float4*)(ar + 36);
        }
        // 3) depth-2 linear perm prefetch
        const int ttF = tt + 2 * nW;
        const int peF = (ttF < nT) ? tilePerm[(ttF << 4) + rA] : -1;

        // 4) cvt A -> bf16, 16 MFMAs
        short8 A0, A1;
        A0[0] = f2bf(ea0.x); A0[1] = f2bf(ea0.y); A0[2] = f2bf(ea0.z); A0[3] = f2bf(ea0.w);
        A0[4] = f2bf(ea1.x); A0[5] = f2bf(ea1.y); A0[6] = f2bf(ea1.z); A0[7] = f2bf(ea1.w);
        A1[0] = f2bf(ea2.x); A1[1] = f2bf(ea2.y); A1[2] = f2bf(ea2.z); A1[3] = f2bf(ea2.w);
        A1[4] = f2bf(ea3.x); A1[5] = f2bf(ea3.y); A1[6] = f2bf(ea3.z); A1[7] = f2bf(ea3.w);
        f32x4 C[8];
#pragma unroll
        for (int t = 0; t < 8; ++t) {
            short8 b0 = *(const short8*)&sBf[t][0][l][0];
            short8 b1 = *(const short8*)&sBf[t][1][l][0];
            f32x4 c = __builtin_amdgcn_mfma_f32_16x16x32_bf16(
                A0, b0, (f32x4){0.f, 0.f, 0.f, 0.f}, 0, 0, 0);
            C[t] = __builtin_amdgcn_mfma_f32_16x16x32_bf16(A1, b1, c, 0, 0, 0);
        }

        // 5) epilogue: relu(msg + h + be), column reduce, 2 atomics
        const float ok0 = (s0 >= 0) ? 1.f : 0.f;
        const float ok1 = (s1 >= 0) ? 1.f : 0.f;
        const float ok2 = (s2 >= 0) ? 1.f : 0.f;
        const float ok3 = (s3 >= 0) ? 1.f : 0.f;
        float pacc[8];
#pragma unroll
        for (int t = 0; t < 8; ++t) {
            float v = fmaxf(C[t][0] + hv0[t] + beT[t], 0.f) * ok0
                    + fmaxf(C[t][1] + hv1[t] + beT[t], 0.f) * ok1
                    + fmaxf(C[t][2] + hv2[t] + beT[t], 0.f) * ok2
                    + fmaxf(C[t][3] + hv3[t] + beT[t], 0.f) * ok3;
            v += __shfl_xor(v, 16);
            v += __shfl_xor(v, 32);
            pacc[t] = v;
        }
        float vlo = (kg == 0) ? pacc[0] : (kg == 1) ? pacc[1] : (kg == 2) ? pacc[2] : pacc[3];
        float vhi = (kg == 0) ? pacc[4] : (kg == 1) ? pacc[5] : (kg == 2) ? pacc[6] : pacc[7];
        float* qp = agg + (size_t)dstC * H + l;
        atomicAdd(qp, vlo);
        atomicAdd(qp + 64, vhi);

        peC = peN; srcC = srcN; dstC = dstN;
        ea0 = eb0; ea1 = eb1; ea2 = eb2; ea3 = eb3;
        peN = peF;
    }
}

// ================= MLP layer 1 (MFMA, hi/lo activations) ======================
// (256,2): 128-reg budget. r5-r12 ran these at 64/85 budgets with ~85-100 live
// -> silent inner-loop spills (~250 us each). Occupancy is irrelevant here
// (memory floor ~30 us); registers are not. s-prefetch restored.
__global__ __launch_bounds__(256, 2) void k_mlp1(
    const float* __restrict__ hN, float* zb, const float* __restrict__ W1,
    const float* __restrict__ b1, const float* __restrict__ epsp, int N)
{
    __shared__ __align__(16) short sBf[8][4][64][8];   // 32 KB W1 frags
    const int tid = threadIdx.x;
    for (int idx = tid; idx < 8 * 4 * 64; idx += 256) {
        int t = idx >> 8, s = (idx >> 6) & 3, ll = idx & 63;
        int ra = ll & 15, kgg = ll >> 4;
        short8 f;
#pragma unroll
        for (int b = 0; b < 8; ++b) {
            int k = (s << 5) + (kgg << 3) + b;
            f[b] = (short)f2bf(W1[k * H + (t << 4) + ra]);
        }
        *(short8*)&sBf[t][s][ll][0] = f;
    }
    __syncthreads();
    const int l = tid & 63, w = tid >> 6;
    const int rA = l & 15, kg = l >> 4;
    const float e1 = 1.f + epsp[0];
    float bT[8];
#pragma unroll
    for (int t = 0; t < 8; ++t) bT[t] = b1[(t << 4) + rA];

    const int nT = (N + CH - 1) / CH;
    for (int tt = blockIdx.x * 4 + w; tt < nT; tt += gridDim.x * 4) {
        const int n0 = tt << 4;
        const int row = min(n0 + rA, N - 1);
        const float* hrow = hN + (size_t)row * H;
        const float* arow = (const float*)zb + (size_t)row * H;
        f32x4 C[8];
#pragma unroll
        for (int t = 0; t < 8; ++t) C[t] = (f32x4){0.f, 0.f, 0.f, 0.f};

        const float* hp = hrow + (kg << 3);
        const float* ap = arow + (kg << 3);
        float4 h0 = *(const float4*)hp, h1 = *(const float4*)(hp + 4);
        float4 g0 = *(const float4*)ap, g1 = *(const float4*)(ap + 4);
#pragma unroll
        for (int s = 0; s < 4; ++s) {
            float4 h0n, h1n, g0n, g1n;
            if (s < 3) {
                const float* hp2 = hrow + ((s + 1) << 5) + (kg << 3);
                const float* ap2 = arow + ((s + 1) << 5) + (kg << 3);
                h0n = *(const float4*)hp2; h1n = *(const float4*)(hp2 + 4);
                g0n = *(const float4*)ap2; g1n = *(const float4*)(ap2 + 4);
            }
            float z[8];
            z[0] = fmaf(e1, h0.x, g0.x); z[1] = fmaf(e1, h0.y, g0.y);
            z[2] = fmaf(e1, h0.z, g0.z); z[3] = fmaf(e1, h0.w, g0.w);
            z[4] = fmaf(e1, h1.x, g1.x); z[5] = fmaf(e1, h1.y, g1.y);
            z[6] = fmaf(e1, h1.z, g1.z); z[7] = fmaf(e1, h1.w, g1.w);
            short8 ah, al;
#pragma unroll
            for (int j = 0; j < 8; ++j) {
                unsigned short hi = f2bf(z[j]);
                ah[j] = (short)hi;
                al[j] = (short)f2bf(z[j] - bf2f(hi));
            }
#pragma unroll
            for (int t = 0; t < 8; ++t) {
                short8 B = *(const short8*)&sBf[t][s][l][0];
                C[t] = __builtin_amdgcn_mfma_f32_16x16x32_bf16(ah, B, C[t], 0, 0, 0);
                C[t] = __builtin_amdgcn_mfma_f32_16x16x32_bf16(al, B, C[t], 0, 0, 0);
            }
            if (s < 3) { h0 = h0n; h1 = h1n; g0 = g0n; g1 = g1n; }
        }
#pragma unroll
        for (int t = 0; t < 8; ++t) {
#pragma unroll
            for (int rg = 0; rg < 4; ++rg) {
                int n = n0 + (kg << 2) + rg;
                float y = fmaxf(C[t][rg] + bT[t], 0.f);
                unsigned short hi = f2bf(y);
                unsigned short lo = f2bf(y - bf2f(hi));
                if (n < N)
                    ((unsigned*)zb)[(size_t)n * H + (t << 4) + rA] =
                        ((unsigned)hi << 16) | (unsigned)lo;
            }
        }
    }
}

// ================= MLP layer 2 + BN stats =================
__global__ __launch_bounds__(256, 2) void k_mlp2(
    float* zb, const float* __restrict__ W2, const float* __restrict__ b2, int N)
{
    __shared__ __align__(16) short sBf[8][4][64][8];   // 32 KB W2 frags
    const int tid = threadIdx.x;
    for (int idx = tid; idx < 8 * 4 * 64; idx += 256) {
        int t = idx >> 8, s = (idx >> 6) & 3, ll = idx & 63;
        int ra = ll & 15, kgg = ll >> 4;
        short8 f;
#pragma unroll
        for (int b = 0; b < 8; ++b) {
            int k = (s << 5) + (kgg << 3) + b;
            f[b] = (short)f2bf(W2[k * H + (t << 4) + ra]);
        }
        *(short8*)&sBf[t][s][ll][0] = f;
    }
    __syncthreads();
    const int l = tid & 63, w = tid >> 6;
    const int rA = l & 15, kg = l >> 4;
    float bT[8];
#pragma unroll
    for (int t = 0; t < 8; ++t) bT[t] = b2[(t << 4) + rA];
    float ps[8], pq[8];
#pragma unroll
    for (int t = 0; t < 8; ++t) { ps[t] = 0.f; pq[t] = 0.f; }

    const int nT = (N + CH - 1) / CH;
    for (int tt = blockIdx.x * 4 + w; tt < nT; tt += gridDim.x * 4) {
        const int n0 = tt << 4;
        const int row = min(n0 + rA, N - 1);
        const unsigned* yrow = (const unsigned*)zb + (size_t)row * H;
        f32x4 C[8];
#pragma unroll
        for (int t = 0; t < 8; ++t) C[t] = (f32x4){0.f, 0.f, 0.f, 0.f};

        const unsigned* yp = yrow + (kg << 3);
        uint4 u0 = *(const uint4*)yp, u1 = *(const uint4*)(yp + 4);
#pragma unroll
        for (int s = 0; s < 4; ++s) {
            uint4 u0n, u1n;
            if (s < 3) {
                const unsigned* yp2 = yrow + ((s + 1) << 5) + (kg << 3);
                u0n = *(const uint4*)yp2; u1n = *(const uint4*)(yp2 + 4);
            }
            short8 ah, al;
            ah[0] = (short)(u0.x >> 16); al[0] = (short)(u0.x & 0xffffu);
            ah[1] = (short)(u0.y >> 16); al[1] = (short)(u0.y & 0xffffu);
            ah[2] = (short)(u0.z >> 16); al[2] = (short)(u0.z & 0xffffu);
            ah[3] = (short)(u0.w >> 16); al[3] = (short)(u0.w & 0xffffu);
            ah[4] = (short)(u1.x >> 16); al[4] = (short)(u1.x & 0xffffu);
            ah[5] = (short)(u1.y >> 16); al[5] = (short)(u1.y & 0xffffu);
            ah[6] = (short)(u1.z >> 16); al[6] = (short)(u1.z & 0xffffu);
            ah[7] = (short)(u1.w >> 16); al[7] = (short)(u1.w & 0xffffu);
#pragma unroll
            for (int t = 0; t < 8; ++t) {
                short8 B = *(const short8*)&sBf[t][s][l][0];
                C[t] = __builtin_amdgcn_mfma_f32_16x16x32_bf16(ah, B, C[t], 0, 0, 0);
                C[t] = __builtin_amdgcn_mfma_f32_16x16x32_bf16(al, B, C[t], 0, 0, 0);
            }
            if (s < 3) { u0 = u0n; u1 = u1n; }
        }
#pragma unroll
        for (int t = 0; t < 8; ++t) {
#pragma unroll
            for (int rg = 0; rg < 4; ++rg) {
                int n = n0 + (kg << 2) + rg;
                float z2 = fmaxf(C[t][rg] + bT[t], 0.f);
                bool v = (n < N);
                if (v) ((float*)zb)[(size_t)n * H + (t << 4) + rA] = z2;
                float zc = v ? z2 : 0.f;
                ps[t] += zc;
                pq[t] += zc * zc;
            }
        }
    }
#pragma unroll
    for (int t = 0; t < 8; ++t) {
        float a = ps[t]; a += __shfl_xor(a, 16); a += __shfl_xor(a, 32); ps[t] = a;
        float b = pq[t]; b += __shfl_xor(b, 16); b += __shfl_xor(b, 32); pq[t] = b;
    }
    if (l < 16) {
#pragma unroll
        for (int t = 0; t < 8; ++t) {
            atomicAdd(&g_stats[(t << 4) + l], ps[t]);
            atomicAdd(&g_stats[128 + (t << 4) + l], pq[t]);
        }
    }
}

// ================= Final: BN finalize folded in (saves a launch) ==============
// out = (h + z2*scale + shift) * valid
__global__ void k_final(const float* __restrict__ hN, const float* __restrict__ valid,
                        const float* __restrict__ gamma, const float* __restrict__ beta,
                        float invN, float* __restrict__ out, int N)
{
    __shared__ float sSc[H], sSh[H];
    if (threadIdx.x < H) {
        int t = threadIdx.x;
        float mean = g_stats[t] * invN;
        float var  = g_stats[H + t] * invN - mean * mean;
        float sc = gamma[t] * rsqrtf(var + 1e-5f);
        sSc[t] = sc;
        sSh[t] = beta[t] - mean * sc;
    }
    __syncthreads();
    const int total = N * (H / 4);
    for (int i = blockIdx.x * blockDim.x + threadIdx.x; i < total;
         i += gridDim.x * blockDim.x) {
        int col4 = i & 31;
        int n = i >> 5;
        float4 z = ((float4*)out)[i];
        float4 hv = ((const float4*)hN)[i];
        float4 sc = *(const float4*)&sSc[col4 * 4];
        float4 sh = *(const float4*)&sSh[col4 * 4];
        float vf = valid[n];
        float4 r;
        r.x = (hv.x + fmaf(z.x, sc.x, sh.x)) * vf;
        r.y = (hv.y + fmaf(z.y, sc.y, sh.y)) * vf;
        r.z = (hv.z + fmaf(z.z, sc.z, sh.z)) * vf;
        r.w = (hv.w + fmaf(z.w, sc.w, sh.w)) * vf;
        ((float4*)out)[i] = r;
    }
}

// ================= Fallback (ws too small): natural-order atomic MFMA =========
__global__ __launch_bounds__(512, 4) void k_edge_a(
    const float* __restrict__ hN, const int* __restrict__ ei,
    const float* __restrict__ ea, const float* __restrict__ We,
    const float* __restrict__ be, float* __restrict__ agg, int E)
{
    __shared__ __align__(16) short sBf[8][2][64][8];
    const int tid = threadIdx.x;
    for (int idx = tid; idx < 8 * 2 * 64; idx += 512) {
        int t = idx >> 7, s = (idx >> 6) & 1, ll = idx & 63;
        int ra = ll & 15, kgg = ll >> 4;
        short8 f;
#pragma unroll
        for (int b = 0; b < 8; ++b) {
            int k = (s << 5) + (kgg << 3) + b;
            f[b] = (short)f2bf(We[k * H + (t << 4) + ra]);
        }
        *(short8*)&sBf[t][s][ll][0] = f;
    }
    const int l = tid & 63, w = tid >> 6;
    const int rA = l & 15, kg = l >> 4;
    float beT[8];
#pragma unroll
    for (int t = 0; t < 8; ++t) beT[t] = be[(t << 4) + rA];
    __syncthreads();

    const int nT = (E + CH - 1) / CH;
    for (int tt = (blockIdx.x << 3) | w; tt < nT; tt += gridDim.x << 3) {
        int e0 = tt * CH;
        const float* ar = ea + (size_t)min(e0 + rA, E - 1) * ED + (kg << 3);
        float4 a0 = *(const float4*)ar,        a1 = *(const float4*)(ar + 4);
        float4 a2 = *(const float4*)(ar + 32), a3 = *(const float4*)(ar + 36);
        int r0 = min(e0 + (kg << 2) + 0, E - 1), r1 = min(e0 + (kg << 2) + 1, E - 1);
        int r2 = min(e0 + (kg << 2) + 2, E - 1), r3 = min(e0 + (kg << 2) + 3, E - 1);
        int s0 = ei[r0], s1 = ei[r1], s2 = ei[r2], s3 = ei[r3];
        int d0 = ei[E + r0], d1 = ei[E + r1], d2 = ei[E + r2], d3 = ei[E + r3];
        float hv0[8], hv1[8], hv2[8], hv3[8];
        const float* hp0 = hN + (size_t)s0 * H + rA;
        const float* hp1 = hN + (size_t)s1 * H + rA;
        const float* hp2 = hN + (size_t)s2 * H + rA;
        const float* hp3 = hN + (size_t)s3 * H + rA;
#pragma unroll
        for (int t = 0; t < 8; ++t) {
            hv0[t] = hp0[t << 4]; hv1[t] = hp1[t << 4];
            hv2[t] = hp2[t << 4]; hv3[t] = hp3[t << 4];
        }
        short8 A0, A1;
        A0[0] = f2bf(a0.x); A0[1] = f2bf(a0.y); A0[2] = f2bf(a0.z); A0[3] = f2bf(a0.w);
        A0[4] = f2bf(a1.x); A0[5] = f2bf(a1.y); A0[6] = f2bf(a1.z); A0[7] = f2bf(a1.w);
        A1[0] = f2bf(a2.x); A1[1] = f2bf(a2.y); A1[2] = f2bf(a2.z); A1[3] = f2bf(a2.w);
        A1[4] = f2bf(a3.x); A1[5] = f2bf(a3.y); A1[6] = f2bf(a3.z); A1[7] = f2bf(a3.w);
        f32x4 C[8];
#pragma unroll
        for (int t = 0; t < 8; ++t) {
            short8 b0 = *(const short8*)&sBf[t][0][l][0];
            short8 b1 = *(const short8*)&sBf[t][1][l][0];
            f32x4 c = __builtin_amdgcn_mfma_f32_16x16x32_bf16(
                A0, b0, (f32x4){0.f, 0.f, 0.f, 0.f}, 0, 0, 0);
            C[t] = __builtin_amdgcn_mfma_f32_16x16x32_bf16(A1, b1, c, 0, 0, 0);
        }
        const int m = E - e0;
        const int r = kg << 2;
        const bool ok0 = (r + 0) < m, ok1 = (r + 1) < m;
        const bool ok2 = (r + 2) < m, ok3 = (r + 3) < m;
        float* q0 = agg + (size_t)d0 * H + rA;
        float* q1 = agg + (size_t)d1 * H + rA;
        float* q2 = agg + (size_t)d2 * H + rA;
        float* q3 = agg + (size_t)d3 * H + rA;
#pragma unroll
        for (int t = 0; t < 8; ++t) {
            if (ok0) atomicAdd(q0 + (t << 4), fmaxf(C[t][0] + hv0[t] + beT[t], 0.f));
            if (ok1) atomicAdd(q1 + (t << 4), fmaxf(C[t][1] + hv1[t] + beT[t], 0.f));
            if (ok2) atomicAdd(q2 + (t << 4), fmaxf(C[t][2] + hv2[t] + beT[t], 0.f));
            if (ok3) atomicAdd(q3 + (t << 4), fmaxf(C[t][3] + hv3[t] + beT[t], 0.f));
        }
    }
}

extern "C" void kernel_launch(void* const* d_in, const int* in_sizes, int n_in,
                              void* d_out, int out_size, void* d_ws, size_t ws_size,
                              hipStream_t stream) {
    const float* hN    = (const float*)d_in[0];
    const int*   ei    = (const int*)d_in[1];
    const float* ea    = (const float*)d_in[2];
    const float* valid = (const float*)d_in[3];
    const float* We    = (const float*)d_in[4];
    const float* be    = (const float*)d_in[5];
    const float* W1    = (const float*)d_in[6];
    const float* b1    = (const float*)d_in[7];
    const float* W2    = (const float*)d_in[8];
    const float* b2    = (const float*)d_in[9];
    const float* epsg  = (const float*)d_in[10];
    const float* gamma = (const float*)d_in[11];
    const float* beta  = (const float*)d_in[12];
    float* out = (float*)d_out;

    const int N = in_sizes[0] / H;
    const int E = in_sizes[1] / 2;

    // ws layout: cnt[N] | cur[N] | toff[N+1] | bsum[SCB] | bpre[SCB] |
    //            tileDst[Tcap] | tilePerm[16*Tcap]
    const int Tcap = (E + 15) / 16 + N;
    const size_t need = ((size_t)3 * N + 1 + 2 * SCB + (size_t)17 * Tcap) * sizeof(int);

    hipMemsetAsync(d_out, 0, (size_t)out_size * sizeof(float), stream);

    if (ws_size >= need) {
        int* cnt      = (int*)d_ws;
        int* cur      = cnt + N;
        int* toff     = cur + N;
        int* bsum     = toff + N + 1;
        int* bpre     = bsum + SCB;
        int* tileDst  = bpre + SCB;
        int* tilePerm = tileDst + Tcap;

        hipMemsetAsync(cnt, 0, (size_t)2 * N * sizeof(int), stream);
        hipMemsetAsync(tilePerm, 0xFF, (size_t)16 * Tcap * sizeof(int), stream);
        k_hist<<<2048, 256, 0, stream>>>(ei, cnt, E);   // also zeroes g_stats
        k_scanA<<<SCB, SCT, 0, stream>>>(cnt, bsum, N);
        k_scanB<<<1, SCB, 0, stream>>>(bsum, bpre, toff + N);
        k_scanC<<<SCB, SCT, 0, stream>>>(cnt, bpre, toff, tileDst, N);
        k_fillp<<<2048, 256, 0, stream>>>(ei, toff, cur, tilePerm, E);
        k_edge_t<<<2048, 256, 0, stream>>>(hN, ei, ea, We, be, toff, tileDst,
                                           tilePerm, out, N, E);
    } else {
        k_zero_stats<<<1, 256, 0, stream>>>();
        k_edge_a<<<1024, 512, 0, stream>>>(hN, ei, ea, We, be, out, E);
    }

    k_mlp1<<<512, 256, 0, stream>>>(hN, out, W1, b1, epsg, N);
    k_mlp2<<<512, 256, 0, stream>>>(out, W2, b2, N);
    k_final<<<2048, 256, 0, stream>>>(hN, valid, gamma, beta, 1.0f / (float)N,
                                      out, N);
}

// Round 15
// 598.044 us; speedup vs baseline: 2.2341x; 1.0413x over previous
//
#include <hip/hip_runtime.h>

#define H 128
#define ED 64
#define CH 16
#define SCB 256
#define SCT 256

typedef __attribute__((ext_vector_type(8))) short short8;
typedef __attribute__((ext_vector_type(4))) float f32x4;
typedef __attribute__((ext_vector_type(4))) unsigned int u32x4;

// stats layout: [0:128) colsum, [128:256) colsumsq
__device__ __align__(16) float g_stats[256];

__device__ __forceinline__ unsigned short f2bf(float f) {
    unsigned u = __float_as_uint(f);
    unsigned r = u + 0x7fffu + ((u >> 16) & 1u);   // RNE
    return (unsigned short)(r >> 16);
}
__device__ __forceinline__ float bf2f(unsigned short h) {
    return __uint_as_float(((unsigned)h) << 16);
}
// non-temporal (evict-first) streaming loads via ext_vector types
// (__builtin_nontemporal_load rejects HIP's class-type float4/uint4).
__device__ __forceinline__ float4 ntld4(const float* p) {
    f32x4 v = __builtin_nontemporal_load((const f32x4*)p);
    return make_float4(v[0], v[1], v[2], v[3]);
}
__device__ __forceinline__ uint4 ntldu4(const unsigned* p) {
    u32x4 v = __builtin_nontemporal_load((const u32x4*)p);
    return make_uint4(v[0], v[1], v[2], v[3]);
}

__global__ void k_zero_stats() {
    if (threadIdx.x < 256) g_stats[threadIdx.x] = 0.f;
}

// ================= padded-tile CSR build =================
__global__ void k_hist(const int* __restrict__ ei, int* __restrict__ cnt, int E) {
    if (blockIdx.x == 0 && threadIdx.x < 256) g_stats[threadIdx.x] = 0.f;
    for (int e = blockIdx.x * blockDim.x + threadIdx.x; e < E;
         e += gridDim.x * blockDim.x)
        atomicAdd(&cnt[ei[E + e]], 1);
}

__global__ __launch_bounds__(SCT) void k_scanA(const int* __restrict__ cnt,
                                               int* __restrict__ bsum, int N) {
    __shared__ int part[SCT];
    const int b = blockIdx.x, t = threadIdx.x;
    const int chunk = (N + SCB - 1) / SCB;
    const int tch = (chunk + SCT - 1) / SCT;
    const int lo = b * chunk + t * tch;
    const int hi = min(lo + tch, min((b + 1) * chunk, N));
    int s = 0;
    for (int i = lo; i < hi; ++i) s += (cnt[i] + 15) >> 4;
    part[t] = s;
    __syncthreads();
    for (int d = SCT / 2; d > 0; d >>= 1) {
        if (t < d) part[t] += part[t + d];
        __syncthreads();
    }
    if (t == 0) bsum[b] = part[0];
}

__global__ __launch_bounds__(SCB) void k_scanB(const int* __restrict__ bsum,
                                               int* __restrict__ bpre,
                                               int* __restrict__ toffN) {
    __shared__ int part[SCB];
    const int t = threadIdx.x;
    int v = bsum[t];
    part[t] = v;
    __syncthreads();
    for (int d = 1; d < SCB; d <<= 1) {
        int x = (t >= d) ? part[t - d] : 0;
        __syncthreads();
        part[t] += x;
        __syncthreads();
    }
    bpre[t] = part[t] - v;
    if (t == SCB - 1) *toffN = part[t];
}

__global__ __launch_bounds__(SCT) void k_scanC(const int* __restrict__ cnt,
                                               const int* __restrict__ bpre,
                                               int* __restrict__ toff,
                                               int* __restrict__ tileDst, int N) {
    __shared__ int part[SCT];
    const int b = blockIdx.x, t = threadIdx.x;
    const int chunk = (N + SCB - 1) / SCB;
    const int tch = (chunk + SCT - 1) / SCT;
    const int lo = b * chunk + t * tch;
    const int hi = min(lo + tch, min((b + 1) * chunk, N));
    int ls = 0;
    for (int i = lo; i < hi; ++i) ls += (cnt[i] + 15) >> 4;
    part[t] = ls;
    __syncthreads();
    for (int d = 1; d < SCT; d <<= 1) {
        int x = (t >= d) ? part[t - d] : 0;
        __syncthreads();
        part[t] += x;
        __syncthreads();
    }
    int run = bpre[b] + part[t] - ls;
    for (int i = lo; i < hi; ++i) {
        toff[i] = run;
        int c = (cnt[i] + 15) >> 4;
        for (int j = 0; j < c; ++j) tileDst[run + j] = i;
        run += c;
    }
}

__global__ void k_fillp(const int* __restrict__ ei, const int* __restrict__ toff,
                        int* __restrict__ cur, int* __restrict__ tilePerm, int E) {
    for (int e = blockIdx.x * blockDim.x + threadIdx.x; e < E;
         e += gridDim.x * blockDim.x) {
        int d = ei[E + e];
        int pos = atomicAdd(&cur[d], 1);
        int tile = toff[d] + (pos >> 4);
        tilePerm[(tile << 4) + (pos & 15)] = e;
    }
}

// ================= Edge kernel: r8 structure + nt ea loads ====================
// A lane map: row = lane&15, k = 8*(lane>>4)+b (+32 2nd K-step)
// C/D lane map: col = lane&15, row = 4*(lane>>4)+reg   (HW-verified r5-r13)
// (256,3): 85-reg budget, uses 84 -> no spill. ea loads are nt (zero reuse)
// so the 410 MB stream stops evicting h (51 MB, want L3-resident).
__global__ __launch_bounds__(256, 3) void k_edge_t(
    const float* __restrict__ hN, const int* __restrict__ ei,
    const float* __restrict__ ea, const float* __restrict__ We,
    const float* __restrict__ be, const int* __restrict__ toff,
    const int* __restrict__ tileDst, const int* __restrict__ tilePerm,
    float* __restrict__ agg, int N, int E)
{
    __shared__ __align__(16) short sBf[8][2][64][8];   // 16 KB B-fragments
    const int tid = threadIdx.x;
    for (int idx = tid; idx < 8 * 2 * 64; idx += 256) {
        int t = idx >> 7, s = (idx >> 6) & 1, ll = idx & 63;
        int ra = ll & 15, kgg = ll >> 4;
        short8 f;
#pragma unroll
        for (int b = 0; b < 8; ++b) {
            int k = (s << 5) + (kgg << 3) + b;
            f[b] = (short)f2bf(We[k * H + (t << 4) + ra]);
        }
        *(short8*)&sBf[t][s][ll][0] = f;
    }
    const int l = tid & 63, w = tid >> 6;
    const int rA = l & 15, kg = l >> 4;
    float beT[8];
#pragma unroll
    for (int t = 0; t < 8; ++t) beT[t] = be[(t << 4) + rA];
    __syncthreads();

    const int nT = toff[N];
    const int gw = (blockIdx.x << 2) | w;
    const int nW = gridDim.x << 2;
    if (gw >= nT) return;

    int peC, srcC, dstC;
    float4 ea0, ea1, ea2, ea3;
    int peN;
    {
        peC = tilePerm[(gw << 4) + rA];
        dstC = tileDst[gw];
        srcC = (peC >= 0) ? ei[peC] : -1;
        const float* ar = ea + (size_t)max(peC, 0) * ED + (kg << 3);
        ea0 = ntld4(ar);      ea1 = ntld4(ar + 4);
        ea2 = ntld4(ar + 32); ea3 = ntld4(ar + 36);
        peN = (gw + nW < nT) ? tilePerm[((gw + nW) << 4) + rA] : -1;
    }

    for (int tt = gw; tt < nT; tt += nW) {
        // 1) distribute srcs, issue hv gathers (normal loads: want L3 hits)
        const int s0 = __shfl(srcC, (kg << 2) + 0);
        const int s1 = __shfl(srcC, (kg << 2) + 1);
        const int s2 = __shfl(srcC, (kg << 2) + 2);
        const int s3 = __shfl(srcC, (kg << 2) + 3);
        float hv0[8], hv1[8], hv2[8], hv3[8];
        {
            const float* hp0 = hN + (size_t)max(s0, 0) * H + rA;
            const float* hp1 = hN + (size_t)max(s1, 0) * H + rA;
            const float* hp2 = hN + (size_t)max(s2, 0) * H + rA;
            const float* hp3 = hN + (size_t)max(s3, 0) * H + rA;
#pragma unroll
            for (int t = 0; t < 8; ++t) {
                hv0[t] = hp0[t << 4]; hv1[t] = hp1[t << 4];
                hv2[t] = hp2[t << 4]; hv3[t] = hp3[t << 4];
            }
        }
        // 2) next tile's src/dst/ea via peN (ea nt)
        const int ttN = tt + nW;
        int srcN = -1, dstN = 0;
        float4 eb0, eb1, eb2, eb3;
        eb0 = eb1 = eb2 = eb3 = make_float4(0.f, 0.f, 0.f, 0.f);
        if (ttN < nT) {
            srcN = (peN >= 0) ? ei[peN] : -1;
            dstN = tileDst[ttN];
            const float* ar = ea + (size_t)max(peN, 0) * ED + (kg << 3);
            eb0 = ntld4(ar);      eb1 = ntld4(ar + 4);
            eb2 = ntld4(ar + 32); eb3 = ntld4(ar + 36);
        }
        // 3) depth-2 linear perm prefetch
        const int ttF = tt + 2 * nW;
        const int peF = (ttF < nT) ? tilePerm[(ttF << 4) + rA] : -1;

        // 4) cvt A -> bf16, 16 MFMAs
        short8 A0, A1;
        A0[0] = f2bf(ea0.x); A0[1] = f2bf(ea0.y); A0[2] = f2bf(ea0.z); A0[3] = f2bf(ea0.w);
        A0[4] = f2bf(ea1.x); A0[5] = f2bf(ea1.y); A0[6] = f2bf(ea1.z); A0[7] = f2bf(ea1.w);
        A1[0] = f2bf(ea2.x); A1[1] = f2bf(ea2.y); A1[2] = f2bf(ea2.z); A1[3] = f2bf(ea2.w);
        A1[4] = f2bf(ea3.x); A1[5] = f2bf(ea3.y); A1[6] = f2bf(ea3.z); A1[7] = f2bf(ea3.w);
        f32x4 C[8];
#pragma unroll
        for (int t = 0; t < 8; ++t) {
            short8 b0 = *(const short8*)&sBf[t][0][l][0];
            short8 b1 = *(const short8*)&sBf[t][1][l][0];
            f32x4 c = __builtin_amdgcn_mfma_f32_16x16x32_bf16(
                A0, b0, (f32x4){0.f, 0.f, 0.f, 0.f}, 0, 0, 0);
            C[t] = __builtin_amdgcn_mfma_f32_16x16x32_bf16(A1, b1, c, 0, 0, 0);
        }

        // 5) epilogue: relu(msg + h + be), column reduce, 2 atomics
        const float ok0 = (s0 >= 0) ? 1.f : 0.f;
        const float ok1 = (s1 >= 0) ? 1.f : 0.f;
        const float ok2 = (s2 >= 0) ? 1.f : 0.f;
        const float ok3 = (s3 >= 0) ? 1.f : 0.f;
        float pacc[8];
#pragma unroll
        for (int t = 0; t < 8; ++t) {
            float v = fmaxf(C[t][0] + hv0[t] + beT[t], 0.f) * ok0
                    + fmaxf(C[t][1] + hv1[t] + beT[t], 0.f) * ok1
                    + fmaxf(C[t][2] + hv2[t] + beT[t], 0.f) * ok2
                    + fmaxf(C[t][3] + hv3[t] + beT[t], 0.f) * ok3;
            v += __shfl_xor(v, 16);
            v += __shfl_xor(v, 32);
            pacc[t] = v;
        }
        float vlo = (kg == 0) ? pacc[0] : (kg == 1) ? pacc[1] : (kg == 2) ? pacc[2] : pacc[3];
        float vhi = (kg == 0) ? pacc[4] : (kg == 1) ? pacc[5] : (kg == 2) ? pacc[6] : pacc[7];
        float* qp = agg + (size_t)dstC * H + l;
        atomicAdd(qp, vlo);
        atomicAdd(qp + 64, vhi);

        peC = peN; srcC = srcN; dstC = dstN;
        ea0 = eb0; ea1 = eb1; ea2 = eb2; ea3 = eb3;
        peN = peF;
    }
}

// ================= MLP layer 1 (MFMA, hi/lo activations) ======================
// (256,2): 128-reg budget (r13-verified fix for silent spills). Streaming
// h/agg loads are nt (one-pass). Cross-s prefetch kept (fits 128 budget).
__global__ __launch_bounds__(256, 2) void k_mlp1(
    const float* __restrict__ hN, float* zb, const float* __restrict__ W1,
    const float* __restrict__ b1, const float* __restrict__ epsp, int N)
{
    __shared__ __align__(16) short sBf[8][4][64][8];   // 32 KB W1 frags
    const int tid = threadIdx.x;
    for (int idx = tid; idx < 8 * 4 * 64; idx += 256) {
        int t = idx >> 8, s = (idx >> 6) & 3, ll = idx & 63;
        int ra = ll & 15, kgg = ll >> 4;
        short8 f;
#pragma unroll
        for (int b = 0; b < 8; ++b) {
            int k = (s << 5) + (kgg << 3) + b;
            f[b] = (short)f2bf(W1[k * H + (t << 4) + ra]);
        }
        *(short8*)&sBf[t][s][ll][0] = f;
    }
    __syncthreads();
    const int l = tid & 63, w = tid >> 6;
    const int rA = l & 15, kg = l >> 4;
    const float e1 = 1.f + epsp[0];
    float bT[8];
#pragma unroll
    for (int t = 0; t < 8; ++t) bT[t] = b1[(t << 4) + rA];

    const int nT = (N + CH - 1) / CH;
    for (int tt = blockIdx.x * 4 + w; tt < nT; tt += gridDim.x * 4) {
        const int n0 = tt << 4;
        const int row = min(n0 + rA, N - 1);
        const float* hrow = hN + (size_t)row * H;
        const float* arow = (const float*)zb + (size_t)row * H;
        f32x4 C[8];
#pragma unroll
        for (int t = 0; t < 8; ++t) C[t] = (f32x4){0.f, 0.f, 0.f, 0.f};

        const float* hp = hrow + (kg << 3);
        const float* ap = arow + (kg << 3);
        float4 h0 = ntld4(hp), h1 = ntld4(hp + 4);
        float4 g0 = ntld4(ap), g1 = ntld4(ap + 4);
#pragma unroll
        for (int s = 0; s < 4; ++s) {
            float4 h0n, h1n, g0n, g1n;
            if (s < 3) {
                const float* hp2 = hrow + ((s + 1) << 5) + (kg << 3);
                const float* ap2 = arow + ((s + 1) << 5) + (kg << 3);
                h0n = ntld4(hp2); h1n = ntld4(hp2 + 4);
                g0n = ntld4(ap2); g1n = ntld4(ap2 + 4);
            }
            float z[8];
            z[0] = fmaf(e1, h0.x, g0.x); z[1] = fmaf(e1, h0.y, g0.y);
            z[2] = fmaf(e1, h0.z, g0.z); z[3] = fmaf(e1, h0.w, g0.w);
            z[4] = fmaf(e1, h1.x, g1.x); z[5] = fmaf(e1, h1.y, g1.y);
            z[6] = fmaf(e1, h1.z, g1.z); z[7] = fmaf(e1, h1.w, g1.w);
            short8 ah, al;
#pragma unroll
            for (int j = 0; j < 8; ++j) {
                unsigned short hi = f2bf(z[j]);
                ah[j] = (short)hi;
                al[j] = (short)f2bf(z[j] - bf2f(hi));
            }
#pragma unroll
            for (int t = 0; t < 8; ++t) {
                short8 B = *(const short8*)&sBf[t][s][l][0];
                C[t] = __builtin_amdgcn_mfma_f32_16x16x32_bf16(ah, B, C[t], 0, 0, 0);
                C[t] = __builtin_amdgcn_mfma_f32_16x16x32_bf16(al, B, C[t], 0, 0, 0);
            }
            if (s < 3) { h0 = h0n; h1 = h1n; g0 = g0n; g1 = g1n; }
        }
#pragma unroll
        for (int t = 0; t < 8; ++t) {
#pragma unroll
            for (int rg = 0; rg < 4; ++rg) {
                int n = n0 + (kg << 2) + rg;
                float y = fmaxf(C[t][rg] + bT[t], 0.f);
                unsigned short hi = f2bf(y);
                unsigned short lo = f2bf(y - bf2f(hi));
                if (n < N)
                    ((unsigned*)zb)[(size_t)n * H + (t << 4) + rA] =
                        ((unsigned)hi << 16) | (unsigned)lo;
            }
        }
    }
}

// ================= MLP layer 2 + BN stats =================
__global__ __launch_bounds__(256, 2) void k_mlp2(
    float* zb, const float* __restrict__ W2, const float* __restrict__ b2, int N)
{
    __shared__ __align__(16) short sBf[8][4][64][8];   // 32 KB W2 frags
    const int tid = threadIdx.x;
    for (int idx = tid; idx < 8 * 4 * 64; idx += 256) {
        int t = idx >> 8, s = (idx >> 6) & 3, ll = idx & 63;
        int ra = ll & 15, kgg = ll >> 4;
        short8 f;
#pragma unroll
        for (int b = 0; b < 8; ++b) {
            int k = (s << 5) + (kgg << 3) + b;
            f[b] = (short)f2bf(W2[k * H + (t << 4) + ra]);
        }
        *(short8*)&sBf[t][s][ll][0] = f;
    }
    __syncthreads();
    const int l = tid & 63, w = tid >> 6;
    const int rA = l & 15, kg = l >> 4;
    float bT[8];
#pragma unroll
    for (int t = 0; t < 8; ++t) bT[t] = b2[(t << 4) + rA];
    float ps[8], pq[8];
#pragma unroll
    for (int t = 0; t < 8; ++t) { ps[t] = 0.f; pq[t] = 0.f; }

    const int nT = (N + CH - 1) / CH;
    for (int tt = blockIdx.x * 4 + w; tt < nT; tt += gridDim.x * 4) {
        const int n0 = tt << 4;
        const int row = min(n0 + rA, N - 1);
        const unsigned* yrow = (const unsigned*)zb + (size_t)row * H;
        f32x4 C[8];
#pragma unroll
        for (int t = 0; t < 8; ++t) C[t] = (f32x4){0.f, 0.f, 0.f, 0.f};

        const unsigned* yp = yrow + (kg << 3);
        uint4 u0 = ntldu4(yp), u1 = ntldu4(yp + 4);
#pragma unroll
        for (int s = 0; s < 4; ++s) {
            uint4 u0n, u1n;
            if (s < 3) {
                const unsigned* yp2 = yrow + ((s + 1) << 5) + (kg << 3);
                u0n = ntldu4(yp2); u1n = ntldu4(yp2 + 4);
            }
            short8 ah, al;
            ah[0] = (short)(u0.x >> 16); al[0] = (short)(u0.x & 0xffffu);
            ah[1] = (short)(u0.y >> 16); al[1] = (short)(u0.y & 0xffffu);
            ah[2] = (short)(u0.z >> 16); al[2] = (short)(u0.z & 0xffffu);
            ah[3] = (short)(u0.w >> 16); al[3] = (short)(u0.w & 0xffffu);
            ah[4] = (short)(u1.x >> 16); al[4] = (short)(u1.x & 0xffffu);
            ah[5] = (short)(u1.y >> 16); al[5] = (short)(u1.y & 0xffffu);
            ah[6] = (short)(u1.z >> 16); al[6] = (short)(u1.z & 0xffffu);
            ah[7] = (short)(u1.w >> 16); al[7] = (short)(u1.w & 0xffffu);
#pragma unroll
            for (int t = 0; t < 8; ++t) {
                short8 B = *(const short8*)&sBf[t][s][l][0];
                C[t] = __builtin_amdgcn_mfma_f32_16x16x32_bf16(ah, B, C[t], 0, 0, 0);
                C[t] = __builtin_amdgcn_mfma_f32_16x16x32_bf16(al, B, C[t], 0, 0, 0);
            }
            if (s < 3) { u0 = u0n; u1 = u1n; }
        }
#pragma unroll
        for (int t = 0; t < 8; ++t) {
#pragma unroll
            for (int rg = 0; rg < 4; ++rg) {
                int n = n0 + (kg << 2) + rg;
                float z2 = fmaxf(C[t][rg] + bT[t], 0.f);
                bool v = (n < N);
                if (v) ((float*)zb)[(size_t)n * H + (t << 4) + rA] = z2;
                float zc = v ? z2 : 0.f;
                ps[t] += zc;
                pq[t] += zc * zc;
            }
        }
    }
#pragma unroll
    for (int t = 0; t < 8; ++t) {
        float a = ps[t]; a += __shfl_xor(a, 16); a += __shfl_xor(a, 32); ps[t] = a;
        float b = pq[t]; b += __shfl_xor(b, 16); b += __shfl_xor(b, 32); pq[t] = b;
    }
    if (l < 16) {
#pragma unroll
        for (int t = 0; t < 8; ++t) {
            atomicAdd(&g_stats[(t << 4) + l], ps[t]);
            atomicAdd(&g_stats[128 + (t << 4) + l], pq[t]);
        }
    }
}

// ================= Final: BN finalize folded in ==============================
__global__ void k_final(const float* __restrict__ hN, const float* __restrict__ valid,
                        const float* __restrict__ gamma, const float* __restrict__ beta,
                        float invN, float* __restrict__ out, int N)
{
    __shared__ float sSc[H], sSh[H];
    if (threadIdx.x < H) {
        int t = threadIdx.x;
        float mean = g_stats[t] * invN;
        float var  = g_stats[H + t] * invN - mean * mean;
        float sc = gamma[t] * rsqrtf(var + 1e-5f);
        sSc[t] = sc;
        sSh[t] = beta[t] - mean * sc;
    }
    __syncthreads();
    const int total = N * (H / 4);
    for (int i = blockIdx.x * blockDim.x + threadIdx.x; i < total;
         i += gridDim.x * blockDim.x) {
        int col4 = i & 31;
        int n = i >> 5;
        float4 z = ((float4*)out)[i];
        float4 hv = ntld4(hN + (size_t)i * 4);
        float4 sc = *(const float4*)&sSc[col4 * 4];
        float4 sh = *(const float4*)&sSh[col4 * 4];
        float vf = valid[n];
        float4 r;
        r.x = (hv.x + fmaf(z.x, sc.x, sh.x)) * vf;
        r.y = (hv.y + fmaf(z.y, sc.y, sh.y)) * vf;
        r.z = (hv.z + fmaf(z.z, sc.z, sh.z)) * vf;
        r.w = (hv.w + fmaf(z.w, sc.w, sh.w)) * vf;
        ((float4*)out)[i] = r;
    }
}

// ================= Fallback (ws too small): natural-order atomic MFMA =========
__global__ __launch_bounds__(512, 4) void k_edge_a(
    const float* __restrict__ hN, const int* __restrict__ ei,
    const float* __restrict__ ea, const float* __restrict__ We,
    const float* __restrict__ be, float* __restrict__ agg, int E)
{
    __shared__ __align__(16) short sBf[8][2][64][8];
    const int tid = threadIdx.x;
    for (int idx = tid; idx < 8 * 2 * 64; idx += 512) {
        int t = idx >> 7, s = (idx >> 6) & 1, ll = idx & 63;
        int ra = ll & 15, kgg = ll >> 4;
        short8 f;
#pragma unroll
        for (int b = 0; b < 8; ++b) {
            int k = (s << 5) + (kgg << 3) + b;
            f[b] = (short)f2bf(We[k * H + (t << 4) + ra]);
        }
        *(short8*)&sBf[t][s][ll][0] = f;
    }
    const int l = tid & 63, w = tid >> 6;
    const int rA = l & 15, kg = l >> 4;
    float beT[8];
#pragma unroll
    for (int t = 0; t < 8; ++t) beT[t] = be[(t << 4) + rA];
    __syncthreads();

    const int nT = (E + CH - 1) / CH;
    for (int tt = (blockIdx.x << 3) | w; tt < nT; tt += gridDim.x << 3) {
        int e0 = tt * CH;
        const float* ar = ea + (size_t)min(e0 + rA, E - 1) * ED + (kg << 3);
        float4 a0 = *(const float4*)ar,        a1 = *(const float4*)(ar + 4);
        float4 a2 = *(const float4*)(ar + 32), a3 = *(const float4*)(ar + 36);
        int r0 = min(e0 + (kg << 2) + 0, E - 1), r1 = min(e0 + (kg << 2) + 1, E - 1);
        int r2 = min(e0 + (kg << 2) + 2, E - 1), r3 = min(e0 + (kg << 2) + 3, E - 1);
        int s0 = ei[r0], s1 = ei[r1], s2 = ei[r2], s3 = ei[r3];
        int d0 = ei[E + r0], d1 = ei[E + r1], d2 = ei[E + r2], d3 = ei[E + r3];
        float hv0[8], hv1[8], hv2[8], hv3[8];
        const float* hp0 = hN + (size_t)s0 * H + rA;
        const float* hp1 = hN + (size_t)s1 * H + rA;
        const float* hp2 = hN + (size_t)s2 * H + rA;
        const float* hp3 = hN + (size_t)s3 * H + rA;
#pragma unroll
        for (int t = 0; t < 8; ++t) {
            hv0[t] = hp0[t << 4]; hv1[t] = hp1[t << 4];
            hv2[t] = hp2[t << 4]; hv3[t] = hp3[t << 4];
        }
        short8 A0, A1;
        A0[0] = f2bf(a0.x); A0[1] = f2bf(a0.y); A0[2] = f2bf(a0.z); A0[3] = f2bf(a0.w);
        A0[4] = f2bf(a1.x); A0[5] = f2bf(a1.y); A0[6] = f2bf(a1.z); A0[7] = f2bf(a1.w);
        A1[0] = f2bf(a2.x); A1[1] = f2bf(a2.y); A1[2] = f2bf(a2.z); A1[3] = f2bf(a2.w);
        A1[4] = f2bf(a3.x); A1[5] = f2bf(a3.y); A1[6] = f2bf(a3.z); A1[7] = f2bf(a3.w);
        f32x4 C[8];
#pragma unroll
        for (int t = 0; t < 8; ++t) {
            short8 b0 = *(const short8*)&sBf[t][0][l][0];
            short8 b1 = *(const short8*)&sBf[t][1][l][0];
            f32x4 c = __builtin_amdgcn_mfma_f32_16x16x32_bf16(
                A0, b0, (f32x4){0.f, 0.f, 0.f, 0.f}, 0, 0, 0);
            C[t] = __builtin_amdgcn_mfma_f32_16x16x32_bf16(A1, b1, c, 0, 0, 0);
        }
        const int m = E - e0;
        const int r = kg << 2;
        const bool ok0 = (r + 0) < m, ok1 = (r + 1) < m;
        const bool ok2 = (r + 2) < m, ok3 = (r + 3) < m;
        float* q0 = agg + (size_t)d0 * H + rA;
        float* q1 = agg + (size_t)d1 * H + rA;
        float* q2 = agg + (size_t)d2 * H + rA;
        float* q3 = agg + (size_t)d3 * H + rA;
#pragma unroll
        for (int t = 0; t < 8; ++t) {
            if (ok0) atomicAdd(q0 + (t << 4), fmaxf(C[t][0] + hv0[t] + beT[t], 0.f));
            if (ok1) atomicAdd(q1 + (t << 4), fmaxf(C[t][1] + hv1[t] + beT[t], 0.f));
            if (ok2) atomicAdd(q2 + (t << 4), fmaxf(C[t][2] + hv2[t] + beT[t], 0.f));
            if (ok3) atomicAdd(q3 + (t << 4), fmaxf(C[t][3] + hv3[t] + beT[t], 0.f));
        }
    }
}

extern "C" void kernel_launch(void* const* d_in, const int* in_sizes, int n_in,
                              void* d_out, int out_size, void* d_ws, size_t ws_size,
                              hipStream_t stream) {
    const float* hN    = (const float*)d_in[0];
    const int*   ei    = (const int*)d_in[1];
    const float* ea    = (const float*)d_in[2];
    const float* valid = (const float*)d_in[3];
    const float* We    = (const float*)d_in[4];
    const float* be    = (const float*)d_in[5];
    const float* W1    = (const float*)d_in[6];
    const float* b1    = (const float*)d_in[7];
    const float* W2    = (const float*)d_in[8];
    const float* b2    = (const float*)d_in[9];
    const float* epsg  = (const float*)d_in[10];
    const float* gamma = (const float*)d_in[11];
    const float* beta  = (const float*)d_in[12];
    float* out = (float*)d_out;

    const int N = in_sizes[0] / H;
    const int E = in_sizes[1] / 2;

    // ws layout: cnt[N] | cur[N] | toff[N+1] | bsum[SCB] | bpre[SCB] |
    //            tileDst[Tcap] | tilePerm[16*Tcap]
    const int Tcap = (E + 15) / 16 + N;
    const size_t need = ((size_t)3 * N + 1 + 2 * SCB + (size_t)17 * Tcap) * sizeof(int);

    (void)hipMemsetAsync(d_out, 0, (size_t)out_size * sizeof(float), stream);

    if (ws_size >= need) {
        int* cnt      = (int*)d_ws;
        int* cur      = cnt + N;
        int* toff     = cur + N;
        int* bsum     = toff + N + 1;
        int* bpre     = bsum + SCB;
        int* tileDst  = bpre + SCB;
        int* tilePerm = tileDst + Tcap;

        (void)hipMemsetAsync(cnt, 0, (size_t)2 * N * sizeof(int), stream);
        (void)hipMemsetAsync(tilePerm, 0xFF, (size_t)16 * Tcap * sizeof(int), stream);
        k_hist<<<2048, 256, 0, stream>>>(ei, cnt, E);   // also zeroes g_stats
        k_scanA<<<SCB, SCT, 0, stream>>>(cnt, bsum, N);
        k_scanB<<<1, SCB, 0, stream>>>(bsum, bpre, toff + N);
        k_scanC<<<SCB, SCT, 0, stream>>>(cnt, bpre, toff, tileDst, N);
        k_fillp<<<2048, 256, 0, stream>>>(ei, toff, cur, tilePerm, E);
        k_edge_t<<<2048, 256, 0, stream>>>(hN, ei, ea, We, be, toff, tileDst,
                                           tilePerm, out, N, E);
    } else {
        k_zero_stats<<<1, 256, 0, stream>>>();
        k_edge_a<<<1024, 512, 0, stream>>>(hN, ei, ea, We, be, out, E);
    }

    k_mlp1<<<512, 256, 0, stream>>>(hN, out, W1, b1, epsg, N);
    k_mlp2<<<512, 256, 0, stream>>>(out, W2, b2, N);
    k_final<<<2048, 256, 0, stream>>>(hN, valid, gamma, beta, 1.0f / (float)N,
                                      out, N);
}